// Round 10
// baseline (289.305 us; speedup 1.0000x reference)
//
#include <hip/hip_runtime.h>

#define N_NODES 100000
#define DIM 128
#define NBUCK 391    // ceil(N/256), bucket = dst>>8 (256 nodes per bucket)
#define CAP 12288    // max edges per bucket in bsort (mean 8187)
#define PT_TILE 8192 // edges per partition block
#define PT_THR 512

typedef unsigned int u32;
typedef unsigned short u16;
typedef __attribute__((ext_vector_type(8))) short bf16x8;
typedef __attribute__((ext_vector_type(4))) float f32x4;

__device__ __forceinline__ float bf16_to_f(u16 v) {
  return __uint_as_float(((u32)v) << 16);
}
__device__ __forceinline__ u16 f_to_bf16(float f) {
  u32 b = __float_as_uint(f);
  b += 0x7fff + ((b >> 16) & 1);  // round-to-nearest-even
  return (u16)(b >> 16);
}
__device__ __forceinline__ float blo(u32 q) { return __uint_as_float(q << 16); }
__device__ __forceinline__ float bhi(u32 q) {
  return __uint_as_float(q & 0xffff0000u);
}
__device__ __forceinline__ u32 packbf(float lo, float hi) {
  return ((u32)f_to_bf16(hi) << 16) | (u32)f_to_bf16(lo);
}

// ============ prep: cvt_W1 + cvt_W2 + bhist (concurrent sections) =========
__global__ __launch_bounds__(256) void prep_kernel(
    const float* __restrict__ W1, u16* __restrict__ Wt1,
    const float* __restrict__ W2, u16* __restrict__ Wt2,
    const int* __restrict__ ei, int* __restrict__ bcnt, int E_) {
  int blk = blockIdx.x;
  if (blk < 64) {
    int id = blk * 256 + threadIdx.x;  // id = c*128 + k
    Wt1[id] = f_to_bf16(W1[(id & 127) * DIM + (id >> 7)]);
  } else if (blk < 128) {
    int id = (blk - 64) * 256 + threadIdx.x;
    Wt2[id] = f_to_bf16(W2[(id & 127) * DIM + (id >> 7)]);
  } else {
    __shared__ int lc[NBUCK];
    for (int i = threadIdx.x; i < NBUCK; i += 256) lc[i] = 0;
    __syncthreads();
    const int* dst = ei + E_;
    int G = 512 * 256;
    int g = (blk - 128) * 256 + threadIdx.x;
    int n4 = E_ >> 2;
    const int4* d4 = (const int4*)dst;
    for (int i = g; i < n4; i += G) {
      int4 v = d4[i];
      atomicAdd(&lc[((u32)v.x) >> 8], 1);
      atomicAdd(&lc[((u32)v.y) >> 8], 1);
      atomicAdd(&lc[((u32)v.z) >> 8], 1);
      atomicAdd(&lc[((u32)v.w) >> 8], 1);
    }
    for (int e = (n4 << 2) + g; e < E_; e += G)
      atomicAdd(&lc[((u32)dst[e]) >> 8], 1);
    __syncthreads();
    for (int i = threadIdx.x; i < NBUCK; i += 256)
      if (lc[i]) atomicAdd(&bcnt[i], lc[i]);
  }
}

__global__ void bscan_kernel(const int* __restrict__ bcnt,
                             int* __restrict__ boffs, int* __restrict__ gcur) {
  __shared__ int s[256];
  int t = threadIdx.x;
  int v0 = (2 * t < NBUCK) ? bcnt[2 * t] : 0;
  int v1 = (2 * t + 1 < NBUCK) ? bcnt[2 * t + 1] : 0;
  int ts = v0 + v1;
  s[t] = ts;
  __syncthreads();
  for (int o = 1; o < 256; o <<= 1) {
    int u = (t >= o) ? s[t - o] : 0;
    __syncthreads();
    s[t] += u;
    __syncthreads();
  }
  int excl = s[t] - ts;
  if (2 * t <= NBUCK) boffs[2 * t] = excl;
  if (2 * t + 1 <= NBUCK) boffs[2 * t + 1] = excl + v0;
  if (2 * t < NBUCK) gcur[2 * t] = excl;
  if (2 * t + 1 < NBUCK) gcur[2 * t + 1] = excl + v0;
}

// ========= partition (+ concurrent cvt_x in disjoint block range) =========
__global__ __launch_bounds__(PT_THR) void part_cvt_kernel(
    const int* __restrict__ ei, int* __restrict__ gcur,
    u32* __restrict__ packed, int E_, const float* __restrict__ x,
    u16* __restrict__ xb) {
  __shared__ u32 keys[PT_TILE];   // 32 KB
  __shared__ u16 bid[PT_TILE];    // 16 KB
  __shared__ int lh[NBUCK];
  __shared__ int lpos[NBUCK];
  __shared__ int gpos[NBUCK];
  __shared__ int ss[PT_THR];
  const int nPart = (E_ + PT_TILE - 1) / PT_TILE;
  const int t = threadIdx.x;

  if (blockIdx.x >= nPart) {
    // cvt_x section: bf16-convert x with float4/ushort4 streaming
    int cb = blockIdx.x - nPart;  // 0..1023
    int total = N_NODES * DIM / 4;
    int stride = 1024 * PT_THR;
    for (int i = cb * PT_THR + t; i < total; i += stride) {
      float4 v = reinterpret_cast<const float4*>(x)[i];
      ushort4 o;
      o.x = f_to_bf16(v.x);
      o.y = f_to_bf16(v.y);
      o.z = f_to_bf16(v.z);
      o.w = f_to_bf16(v.w);
      reinterpret_cast<ushort4*>(xb)[i] = o;
    }
    return;
  }

  const int base = blockIdx.x * PT_TILE;
  const int cnt = min(PT_TILE, E_ - base);

  for (int i = t; i < NBUCK; i += PT_THR) lh[i] = 0;
  __syncthreads();

  u32 pk[16];
  int bb[16];
#pragma unroll
  for (int k = 0; k < 16; ++k) {
    int e = base + k * PT_THR + t;
    if (k * PT_THR + t < cnt) {
      int src = ei[e];
      u32 dst = (u32)ei[E_ + e];
      bb[k] = (int)(dst >> 8);
      pk[k] = (u32)src | ((dst & 255u) << 17);
      atomicAdd(&lh[bb[k]], 1);
    } else {
      bb[k] = -1;
    }
  }
  __syncthreads();

  int v = (t < NBUCK) ? lh[t] : 0;
  ss[t] = v;
  __syncthreads();
  for (int o = 1; o < PT_THR; o <<= 1) {
    int u = (t >= o) ? ss[t - o] : 0;
    __syncthreads();
    ss[t] += u;
    __syncthreads();
  }
  if (t < NBUCK) {
    lpos[t] = ss[t] - v;
    if (v > 0) gpos[t] = atomicAdd(&gcur[t], v);
  }
  __syncthreads();

#pragma unroll
  for (int k = 0; k < 16; ++k) {
    if (bb[k] >= 0) {
      int p = atomicAdd(&lpos[bb[k]], 1);
      keys[p] = pk[k];
      bid[p] = (u16)bb[k];
    }
  }
  __syncthreads();

  for (int i = t; i < cnt; i += PT_THR) {
    int b = bid[i];
    int startb = lpos[b] - lh[b];
    packed[gpos[b] + (i - startb)] = keys[i];
  }
}

// Per-bucket counting sort in LDS -> exact CSR + per-node offsets.
__global__ __launch_bounds__(256) void bsort_kernel(u32* __restrict__ packed,
                                                    const int* __restrict__ boffs,
                                                    int* __restrict__ offs,
                                                    int E_) {
  __shared__ u32 sorted_[CAP];  // 48 KB
  __shared__ int hist[256], cur[256], ss[256];
  const int b = blockIdx.x, t = threadIdx.x;
  int base = boffs[b];
  int cnt = boffs[b + 1] - base;
  if (cnt > CAP) cnt = CAP;
  hist[t] = 0;
  __syncthreads();
  for (int i = t; i < cnt; i += 256) atomicAdd(&hist[packed[base + i] >> 17], 1);
  __syncthreads();
  int hv = hist[t];
  ss[t] = hv;
  __syncthreads();
  for (int o = 1; o < 256; o <<= 1) {
    int u = (t >= o) ? ss[t - o] : 0;
    __syncthreads();
    ss[t] += u;
    __syncthreads();
  }
  int excl = ss[t] - hv;
  cur[t] = excl;
  __syncthreads();
  for (int i = t; i < cnt; i += 256) {
    u32 v = packed[base + i];
    int p = atomicAdd(&cur[v >> 17], 1);
    sorted_[p] = v & 0x1FFFFu;
  }
  __syncthreads();
  for (int i = t; i < cnt; i += 256) packed[base + i] = sorted_[i];
  int node = b * 256 + t;
  if (node < N_NODES) offs[node] = base + excl;
  if (b == 0 && t == 0) offs[N_NODES] = E_;
}

// ========== Gather v4: 16B/lane loads, 16 lanes/row, 4 edges/wave =========
__global__ __launch_bounds__(256) void gather_bf16_kernel(
    const uint4* __restrict__ xb4, const int* __restrict__ offs,
    const int* __restrict__ csr, uint4* __restrict__ hb4) {
  int n = blockIdx.x * 4 + (threadIdx.x >> 6);
  int lane = threadIdx.x & 63;
  int g = lane >> 4;
  int l = lane & 15;
  int beg = offs[n], end = offs[n + 1];
  float a0 = 0.f, a1 = 0.f, a2 = 0.f, a3 = 0.f;
  float a4 = 0.f, a5 = 0.f, a6 = 0.f, a7 = 0.f;
  if (g == 0) {  // self row
    uint4 q = xb4[(size_t)n * 16 + l];
    a0 = blo(q.x); a1 = bhi(q.x);
    a2 = blo(q.y); a3 = bhi(q.y);
    a4 = blo(q.z); a5 = bhi(q.z);
    a6 = blo(q.w); a7 = bhi(q.w);
  }
  int j = beg + g;
  for (; j + 12 < end; j += 16) {
    int s0 = csr[j], s1 = csr[j + 4], s2 = csr[j + 8], s3 = csr[j + 12];
    uint4 q0 = xb4[(size_t)s0 * 16 + l];
    uint4 q1 = xb4[(size_t)s1 * 16 + l];
    uint4 q2 = xb4[(size_t)s2 * 16 + l];
    uint4 q3 = xb4[(size_t)s3 * 16 + l];
    a0 += blo(q0.x); a1 += bhi(q0.x);
    a2 += blo(q0.y); a3 += bhi(q0.y);
    a4 += blo(q0.z); a5 += bhi(q0.z);
    a6 += blo(q0.w); a7 += bhi(q0.w);
    a0 += blo(q1.x); a1 += bhi(q1.x);
    a2 += blo(q1.y); a3 += bhi(q1.y);
    a4 += blo(q1.z); a5 += bhi(q1.z);
    a6 += blo(q1.w); a7 += bhi(q1.w);
    a0 += blo(q2.x); a1 += bhi(q2.x);
    a2 += blo(q2.y); a3 += bhi(q2.y);
    a4 += blo(q2.z); a5 += bhi(q2.z);
    a6 += blo(q2.w); a7 += bhi(q2.w);
    a0 += blo(q3.x); a1 += bhi(q3.x);
    a2 += blo(q3.y); a3 += bhi(q3.y);
    a4 += blo(q3.z); a5 += bhi(q3.z);
    a6 += blo(q3.w); a7 += bhi(q3.w);
  }
  for (; j < end; j += 4) {
    uint4 q = xb4[(size_t)csr[j] * 16 + l];
    a0 += blo(q.x); a1 += bhi(q.x);
    a2 += blo(q.y); a3 += bhi(q.y);
    a4 += blo(q.z); a5 += bhi(q.z);
    a6 += blo(q.w); a7 += bhi(q.w);
  }
  a0 += __shfl_xor(a0, 16); a1 += __shfl_xor(a1, 16);
  a2 += __shfl_xor(a2, 16); a3 += __shfl_xor(a3, 16);
  a4 += __shfl_xor(a4, 16); a5 += __shfl_xor(a5, 16);
  a6 += __shfl_xor(a6, 16); a7 += __shfl_xor(a7, 16);
  a0 += __shfl_xor(a0, 32); a1 += __shfl_xor(a1, 32);
  a2 += __shfl_xor(a2, 32); a3 += __shfl_xor(a3, 32);
  a4 += __shfl_xor(a4, 32); a5 += __shfl_xor(a5, 32);
  a6 += __shfl_xor(a6, 32); a7 += __shfl_xor(a7, 32);
  if (g == 0) {
    uint4 o;
    o.x = packbf(a0, a1);
    o.y = packbf(a2, a3);
    o.z = packbf(a4, a5);
    o.w = packbf(a6, a7);
    hb4[(size_t)n * 16 + l] = o;
  }
}

// ===== MFMA MLP: writes bf16 h2 in place in hb + atomic BN stats ==========
__global__ __launch_bounds__(256) void mlp_mfma_kernel(
    u16* __restrict__ hb, const u16* __restrict__ Wt1,
    const u16* __restrict__ Wt2, const float* __restrict__ b1,
    const float* __restrict__ b2, float* __restrict__ stats) {
  __shared__ u16 sH1[4][16 * DIM];  // 16 KB
  __shared__ float sS[4][128], sQ[4][128];  // 4 KB
  const int tid = threadIdx.x;
  const int wv = tid >> 6;
  const int lane = tid & 63;
  const int lr = lane & 15;
  const int lq = lane >> 4;
  const int row0 = blockIdx.x * 64 + wv * 16;

  // ---- layer 1 ----
  bf16x8 a[4];
  {
    int r = row0 + lr;
    if (r > N_NODES - 1) r = N_NODES - 1;
#pragma unroll
    for (int ks = 0; ks < 4; ++ks)
      a[ks] = *reinterpret_cast<const bf16x8*>(hb + (size_t)r * DIM + ks * 32 +
                                               lq * 8);
  }
  f32x4 acc[8];
#pragma unroll
  for (int ct = 0; ct < 8; ++ct) {
    f32x4 c = {0.f, 0.f, 0.f, 0.f};
#pragma unroll
    for (int ks = 0; ks < 4; ++ks) {
      bf16x8 b = *reinterpret_cast<const bf16x8*>(
          Wt1 + (ct * 16 + lr) * DIM + ks * 32 + lq * 8);
      c = __builtin_amdgcn_mfma_f32_16x16x32_bf16(a[ks], b, c, 0, 0, 0);
    }
    acc[ct] = c;
  }
  char* slab = reinterpret_cast<char*>(&sH1[wv][0]);
#pragma unroll
  for (int ct = 0; ct < 8; ++ct) {
    int c = ct * 16 + lr;
    float bias = b1[c];
#pragma unroll
    for (int j = 0; j < 4; ++j) {
      int rl = lq * 4 + j;
      float y = fmaxf(acc[ct][j] + bias, 0.f);
      int byte = rl * 256 + ((c * 2) ^ ((rl & 7) << 4));
      *reinterpret_cast<u16*>(slab + byte) = f_to_bf16(y);
    }
  }
  __syncthreads();

  // ---- layer 2 ----
  bf16x8 a2[4];
#pragma unroll
  for (int ks = 0; ks < 4; ++ks) {
    int byte = lr * 256 + (((ks * 32 + lq * 8) * 2) ^ ((lr & 7) << 4));
    a2[ks] = *reinterpret_cast<const bf16x8*>(slab + byte);
  }
#pragma unroll
  for (int ct = 0; ct < 8; ++ct) {
    f32x4 c = {0.f, 0.f, 0.f, 0.f};
#pragma unroll
    for (int ks = 0; ks < 4; ++ks) {
      bf16x8 b = *reinterpret_cast<const bf16x8*>(
          Wt2 + (ct * 16 + lr) * DIM + ks * 32 + lq * 8);
      c = __builtin_amdgcn_mfma_f32_16x16x32_bf16(a2[ks], b, c, 0, 0, 0);
    }
    acc[ct] = c;
  }
  // ---- epilogue: bf16 h2 back into hb + per-column (s, ss) of quantized ----
  float ls[8], lss[8];
#pragma unroll
  for (int ct = 0; ct < 8; ++ct) {
    int c = ct * 16 + lr;
    float bias = b2[c];
    ls[ct] = 0.f;
    lss[ct] = 0.f;
#pragma unroll
    for (int j = 0; j < 4; ++j) {
      int r = row0 + lq * 4 + j;
      float y = fmaxf(acc[ct][j] + bias, 0.f);
      u16 yq = f_to_bf16(y);
      float yf = bf16_to_f(yq);
      if (r < N_NODES) {
        hb[(size_t)r * DIM + c] = yq;
        ls[ct] += yf;
        lss[ct] += yf * yf;
      }
    }
  }
#pragma unroll
  for (int ct = 0; ct < 8; ++ct) {
    float s = ls[ct], q = lss[ct];
    s += __shfl_xor(s, 16);
    q += __shfl_xor(q, 16);
    s += __shfl_xor(s, 32);
    q += __shfl_xor(q, 32);
    if (lq == 0) {
      sS[wv][ct * 16 + lr] = s;
      sQ[wv][ct * 16 + lr] = q;
    }
  }
  __syncthreads();
  {
    int t = tid;
    float v;
    if (t < 128)
      v = sS[0][t] + sS[1][t] + sS[2][t] + sS[3][t];
    else
      v = sQ[0][t - 128] + sQ[1][t - 128] + sQ[2][t - 128] + sQ[3][t - 128];
    atomicAdd(&stats[t], v);
  }
}

// ======= BN apply: per-block scale/shift from stats, bf16 in, f32 out =====
__global__ __launch_bounds__(256) void bn_apply_bf16_kernel(
    const uint4* __restrict__ hb4, const float* __restrict__ stats,
    const float* __restrict__ gamma, const float* __restrict__ beta,
    float4* __restrict__ out4) {
  __shared__ float sSc[128], sSh[128];
  int t = threadIdx.x;
  if (t < 128) {
    float mean = stats[t] / (float)N_NODES;
    float var = stats[128 + t] / (float)N_NODES - mean * mean;
    float scale = gamma[t] * rsqrtf(var + 1e-5f);
    sSc[t] = scale;
    sSh[t] = beta[t] - mean * scale;
  }
  __syncthreads();
  int total = N_NODES * 16;  // uint4 per row of 128 bf16
  int stride = gridDim.x * 256;
  for (int i = blockIdx.x * 256 + t; i < total; i += stride) {
    uint4 q = hb4[i];
    int cb = (i & 15) * 8;
    float4 o0, o1;
    o0.x = blo(q.x) * sSc[cb + 0] + sSh[cb + 0];
    o0.y = bhi(q.x) * sSc[cb + 1] + sSh[cb + 1];
    o0.z = blo(q.y) * sSc[cb + 2] + sSh[cb + 2];
    o0.w = bhi(q.y) * sSc[cb + 3] + sSh[cb + 3];
    o1.x = blo(q.z) * sSc[cb + 4] + sSh[cb + 4];
    o1.y = bhi(q.z) * sSc[cb + 5] + sSh[cb + 5];
    o1.z = blo(q.w) * sSc[cb + 6] + sSh[cb + 6];
    o1.w = bhi(q.w) * sSc[cb + 7] + sSh[cb + 7];
    out4[2 * i] = o0;
    out4[2 * i + 1] = o1;
  }
}

// ======================= Fallback kernels =======================
__global__ __launch_bounds__(256) void hist_kernel(const int* __restrict__ ei,
                                                   int* __restrict__ deg,
                                                   int E_) {
  int stride = gridDim.x * blockDim.x;
  for (int e = blockIdx.x * blockDim.x + threadIdx.x; e < E_; e += stride)
    atomicAdd(&deg[ei[E_ + e]], 1);
}

__global__ __launch_bounds__(256) void scan_block_kernel(
    const int* __restrict__ deg, int* __restrict__ offs,
    int* __restrict__ partials, int n) {
  const int tid = threadIdx.x;
  int g = blockIdx.x * 1024 + tid * 4;
  int v0 = (g + 0 < n) ? deg[g + 0] : 0;
  int v1 = (g + 1 < n) ? deg[g + 1] : 0;
  int v2 = (g + 2 < n) ? deg[g + 2] : 0;
  int v3 = (g + 3 < n) ? deg[g + 3] : 0;
  int tsum = v0 + v1 + v2 + v3;
  __shared__ int s[256];
  s[tid] = tsum;
  __syncthreads();
  for (int off = 1; off < 256; off <<= 1) {
    int t = (tid >= off) ? s[tid - off] : 0;
    __syncthreads();
    s[tid] += t;
    __syncthreads();
  }
  int excl = s[tid] - tsum;
  if (g + 0 < n) offs[g + 0] = excl;
  if (g + 1 < n) offs[g + 1] = excl + v0;
  if (g + 2 < n) offs[g + 2] = excl + v0 + v1;
  if (g + 3 < n) offs[g + 3] = excl + v0 + v1 + v2;
  if (tid == 255) partials[blockIdx.x] = s[255];
}

__global__ void scan_partials_kernel(int* __restrict__ partials, int nb) {
  const int tid = threadIdx.x;
  int v = (tid < nb) ? partials[tid] : 0;
  __shared__ int s[128];
  s[tid] = v;
  __syncthreads();
  for (int off = 1; off < 128; off <<= 1) {
    int t = (tid >= off) ? s[tid - off] : 0;
    __syncthreads();
    s[tid] += t;
    __syncthreads();
  }
  if (tid < nb) partials[tid] = s[tid] - v;
}

__global__ __launch_bounds__(256) void scan_add_kernel(
    int* __restrict__ offs, int* __restrict__ cursor,
    const int* __restrict__ partials, int n, int E_) {
  int g = blockIdx.x * blockDim.x + threadIdx.x;
  if (g < n) {
    int v = offs[g] + partials[g >> 10];
    offs[g] = v;
    cursor[g] = v;
  }
  if (g == 0) offs[n] = E_;
}

__global__ __launch_bounds__(256) void fill_kernel(const int* __restrict__ ei,
                                                   int* __restrict__ cursor,
                                                   int* __restrict__ csr,
                                                   int E_) {
  const int G = gridDim.x * blockDim.x;
  int g = blockIdx.x * blockDim.x + threadIdx.x;
  for (long long base = g; base < E_; base += (long long)G * 8) {
    int src[8], dst[8], pos[8];
#pragma unroll
    for (int k = 0; k < 8; ++k) {
      long long e = base + (long long)k * G;
      src[k] = (e < E_) ? ei[e] : -1;
      dst[k] = (e < E_) ? ei[E_ + e] : 0;
    }
#pragma unroll
    for (int k = 0; k < 8; ++k)
      if (src[k] >= 0) pos[k] = atomicAdd(&cursor[dst[k]], 1);
#pragma unroll
    for (int k = 0; k < 8; ++k)
      if (src[k] >= 0) csr[pos[k]] = src[k];
  }
}

__global__ __launch_bounds__(128) void gather_f32_kernel(
    const float* __restrict__ x, const int* __restrict__ offs,
    const int* __restrict__ csr, float* __restrict__ h) {
  int n = blockIdx.x;
  int c = threadIdx.x;
  int beg = offs[n], end = offs[n + 1];
  float acc = x[(size_t)n * DIM + c];
  for (int j = beg; j < end; ++j) acc += x[(size_t)csr[j] * DIM + c];
  h[(size_t)n * DIM + c] = acc;
}

__global__ __launch_bounds__(256) void scatter_kernel(
    const float* __restrict__ x, const int* __restrict__ ei,
    float* __restrict__ h, int E_) {
  long long total = (long long)E_ * 32;
  long long stride = (long long)gridDim.x * blockDim.x;
  for (long long idx = (long long)blockIdx.x * blockDim.x + threadIdx.x;
       idx < total; idx += stride) {
    int e = (int)(idx >> 5);
    int q = (int)(idx & 31);
    float4 v =
        *reinterpret_cast<const float4*>(x + (size_t)ei[e] * DIM + q * 4);
    float* p = h + (size_t)ei[E_ + e] * DIM + q * 4;
    atomicAdd(p + 0, v.x);
    atomicAdd(p + 1, v.y);
    atomicAdd(p + 2, v.z);
    atomicAdd(p + 3, v.w);
  }
}

__global__ __launch_bounds__(256) void add_x_kernel(const float* __restrict__ x,
                                                    float* __restrict__ h) {
  size_t total = (size_t)N_NODES * DIM / 4;
  size_t stride = (size_t)gridDim.x * blockDim.x;
  for (size_t i = (size_t)blockIdx.x * blockDim.x + threadIdx.x; i < total;
       i += stride) {
    float4 v = reinterpret_cast<float4*>(h)[i];
    float4 xv = reinterpret_cast<const float4*>(x)[i];
    v.x += xv.x; v.y += xv.y; v.z += xv.z; v.w += xv.w;
    reinterpret_cast<float4*>(h)[i] = v;
  }
}

__global__ __launch_bounds__(256) void mlp_valu_kernel(
    float* hbuf, const float* __restrict__ W1, const float* __restrict__ b1,
    const float* __restrict__ W2, const float* __restrict__ b2) {
  __shared__ float sW[DIM * DIM];
  __shared__ float sH[32][DIM];
  const int tid = threadIdx.x;
  const int col = tid & 127;
  const int rhalf = tid >> 7;
  const int row0 = blockIdx.x * 32;

  for (int i = tid; i < DIM * DIM; i += 256) sW[i] = W1[i];
  for (int i = tid; i < 32 * DIM; i += 256) {
    int r = i >> 7, c = i & 127;
    sH[r][c] = hbuf[(size_t)(row0 + r) * DIM + c];
  }
  __syncthreads();
  float acc[16];
  float bias = b1[col];
#pragma unroll
  for (int j = 0; j < 16; ++j) acc[j] = bias;
#pragma unroll 4
  for (int k = 0; k < DIM; ++k) {
    float w = sW[k * DIM + col];
#pragma unroll
    for (int j = 0; j < 16; ++j) acc[j] = fmaf(sH[2 * j + rhalf][k], w, acc[j]);
  }
  __syncthreads();
  for (int i = tid; i < DIM * DIM; i += 256) sW[i] = W2[i];
#pragma unroll
  for (int j = 0; j < 16; ++j) sH[2 * j + rhalf][col] = fmaxf(acc[j], 0.f);
  __syncthreads();
  float bias2 = b2[col];
#pragma unroll
  for (int j = 0; j < 16; ++j) acc[j] = bias2;
#pragma unroll 4
  for (int k = 0; k < DIM; ++k) {
    float w = sW[k * DIM + col];
#pragma unroll
    for (int j = 0; j < 16; ++j) acc[j] = fmaf(sH[2 * j + rhalf][k], w, acc[j]);
  }
#pragma unroll
  for (int j = 0; j < 16; ++j)
    hbuf[(size_t)(row0 + 2 * j + rhalf) * DIM + col] = fmaxf(acc[j], 0.f);
}

__global__ __launch_bounds__(256) void bn_stats_kernel(
    const float* __restrict__ h, float* __restrict__ stats) {
  int col = threadIdx.x & 127;
  int rsub = threadIdx.x >> 7;
  int rstep = gridDim.x * 2;
  float s = 0.f, ss = 0.f;
  for (int r = blockIdx.x * 2 + rsub; r < N_NODES; r += rstep) {
    float v = h[(size_t)r * DIM + col];
    s += v;
    ss += v * v;
  }
  __shared__ float ls[256], lss[256];
  ls[threadIdx.x] = s;
  lss[threadIdx.x] = ss;
  __syncthreads();
  if (threadIdx.x < 128) {
    atomicAdd(&stats[col], ls[threadIdx.x] + ls[threadIdx.x + 128]);
    atomicAdd(&stats[DIM + col], lss[threadIdx.x] + lss[threadIdx.x + 128]);
  }
}

__global__ void bn_scale_kernel(const float* __restrict__ stats,
                                const float* __restrict__ gamma,
                                const float* __restrict__ beta,
                                float* __restrict__ sc) {
  int c = threadIdx.x;  // 128
  float mean = stats[c] / (float)N_NODES;
  float var = stats[DIM + c] / (float)N_NODES - mean * mean;
  float scale = gamma[c] * rsqrtf(var + 1e-5f);
  sc[c] = scale;
  sc[DIM + c] = beta[c] - mean * scale;
}

__global__ __launch_bounds__(256) void bn_apply_kernel(
    float* __restrict__ h, const float* __restrict__ sc) {
  size_t total = (size_t)N_NODES * DIM / 4;
  size_t stride = (size_t)gridDim.x * blockDim.x;
  for (size_t i = (size_t)blockIdx.x * blockDim.x + threadIdx.x; i < total;
       i += stride) {
    float4 v = reinterpret_cast<float4*>(h)[i];
    int c = (int)((i * 4) & 127);
    v.x = v.x * sc[c + 0] + sc[DIM + c + 0];
    v.y = v.y * sc[c + 1] + sc[DIM + c + 1];
    v.z = v.z * sc[c + 2] + sc[DIM + c + 2];
    v.w = v.w * sc[c + 3] + sc[DIM + c + 3];
    reinterpret_cast<float4*>(h)[i] = v;
  }
}

extern "C" void kernel_launch(void* const* d_in, const int* in_sizes, int n_in,
                              void* d_out, int out_size, void* d_ws,
                              size_t ws_size, hipStream_t stream) {
  const float* x = (const float*)d_in[0];
  const int* ei = (const int*)d_in[1];
  const float* W1 = (const float*)d_in[3];
  const float* b1 = (const float*)d_in[4];
  const float* W2 = (const float*)d_in[5];
  const float* b2 = (const float*)d_in[6];
  const float* gamma = (const float*)d_in[7];
  const float* beta = (const float*)d_in[8];
  float* out = (float*)d_out;
  int E_ = in_sizes[1] / 2;

  // ---- full-path workspace layout (16B-aligned fields) ----
  const size_t XB_B = (size_t)N_NODES * DIM * 2;  // 25.6e6
  char* w = (char*)d_ws;
  size_t off = 0;
  u16* xb = (u16*)(w + off); off += XB_B;
  u16* hb = (u16*)(w + off); off += XB_B;
  u16* Wt1 = (u16*)(w + off); off += 32768;
  u16* Wt2 = (u16*)(w + off); off += 32768;
  u32* packed = (u32*)(w + off); off += (size_t)E_ * 4;      // doubles as csr
  int* offs = (int*)(w + off); off += ((size_t)N_NODES + 4) * 4;
  int* bcnt = (int*)(w + off); off += 1600;
  float* stats = (float*)(w + off); off += 3072;
  int* boffs = (int*)(w + off); off += 1600;
  int* gcur = (int*)(w + off); off += 1600;
  size_t need_full = off;

  // ---- CSR-only fallback layout ----
  int* f_offs = (int*)d_ws;
  int* f_cursor = f_offs + N_NODES + 1;
  int* f_partials = f_cursor + N_NODES;
  int* f_csr = f_partials + 128;
  float* f_stats = (float*)(f_csr + E_);
  size_t need_csr = ((size_t)2 * N_NODES + 129 + E_) * 4 + 3072;

  const int nScanBlocks = (N_NODES + 1023) / 1024;  // 98
  const int nEdgeBlocks = (E_ + 2047) / 2048;
  const int nPartBlocks = (E_ + PT_TILE - 1) / PT_TILE;
  const int nMlpBlocks = (N_NODES + 63) / 64;  // 1563

  if (ws_size >= need_full) {
    hipMemsetAsync(bcnt, 0, 1600 + 3072, stream);  // bcnt + stats
    prep_kernel<<<640, 256, 0, stream>>>(W1, Wt1, W2, Wt2, ei, bcnt, E_);
    bscan_kernel<<<1, 256, 0, stream>>>(bcnt, boffs, gcur);
    part_cvt_kernel<<<nPartBlocks + 1024, PT_THR, 0, stream>>>(
        ei, gcur, packed, E_, x, xb);
    bsort_kernel<<<NBUCK, 256, 0, stream>>>(packed, boffs, offs, E_);
    gather_bf16_kernel<<<N_NODES / 4, 256, 0, stream>>>(
        (const uint4*)xb, offs, (const int*)packed, (uint4*)hb);
    mlp_mfma_kernel<<<nMlpBlocks, 256, 0, stream>>>(hb, Wt1, Wt2, b1, b2,
                                                    stats);
    bn_apply_bf16_kernel<<<2048, 256, 0, stream>>>(
        (const uint4*)hb, stats, gamma, beta, (float4*)out);
  } else if (ws_size >= need_csr) {
    hipMemsetAsync(f_cursor, 0, (size_t)N_NODES * sizeof(int), stream);
    hipMemsetAsync(f_stats, 0, 768 * sizeof(float), stream);
    hist_kernel<<<2048, 256, 0, stream>>>(ei, f_cursor, E_);
    scan_block_kernel<<<nScanBlocks, 256, 0, stream>>>(f_cursor, f_offs,
                                                       f_partials, N_NODES);
    scan_partials_kernel<<<1, 128, 0, stream>>>(f_partials, nScanBlocks);
    scan_add_kernel<<<(N_NODES + 255) / 256, 256, 0, stream>>>(
        f_offs, f_cursor, f_partials, N_NODES, E_);
    fill_kernel<<<nEdgeBlocks, 256, 0, stream>>>(ei, f_cursor, f_csr, E_);
    gather_f32_kernel<<<N_NODES, 128, 0, stream>>>(x, f_offs, f_csr, out);
    mlp_valu_kernel<<<(N_NODES + 31) / 32, 256, 0, stream>>>(out, W1, b1, W2,
                                                             b2);
    bn_stats_kernel<<<1024, 256, 0, stream>>>(out, f_stats);
    bn_scale_kernel<<<1, 128, 0, stream>>>(f_stats, gamma, beta, f_stats + 256);
    bn_apply_kernel<<<2048, 256, 0, stream>>>(out, f_stats + 256);
  } else {
    float* s2 = (float*)d_ws;
    hipMemsetAsync(out, 0, (size_t)N_NODES * DIM * sizeof(float), stream);
    hipMemsetAsync(s2, 0, 768 * sizeof(float), stream);
    scatter_kernel<<<4096, 256, 0, stream>>>(x, ei, out, E_);
    add_x_kernel<<<2048, 256, 0, stream>>>(x, out);
    mlp_valu_kernel<<<(N_NODES + 31) / 32, 256, 0, stream>>>(out, W1, b1, W2,
                                                             b2);
    bn_stats_kernel<<<1024, 256, 0, stream>>>(out, s2);
    bn_scale_kernel<<<1, 128, 0, stream>>>(s2, gamma, beta, s2 + 256);
    bn_apply_kernel<<<2048, 256, 0, stream>>>(out, s2 + 256);
  }
}

// Round 11
// 276.365 us; speedup vs baseline: 1.0468x; 1.0468x over previous
//
#include <hip/hip_runtime.h>

#define N_NODES 100000
#define DIM 128
#define NBUCK 391    // ceil(N/256), bucket = dst>>8 (256 nodes per bucket)
#define CAP 12288    // max edges per bucket in bsort (mean 8187)
#define PT_TILE 8192 // edges per partition block
#define PT_THR 512

typedef unsigned int u32;
typedef unsigned short u16;
typedef __attribute__((ext_vector_type(8))) short bf16x8;
typedef __attribute__((ext_vector_type(4))) float f32x4;

__device__ __forceinline__ float bf16_to_f(u16 v) {
  return __uint_as_float(((u32)v) << 16);
}
__device__ __forceinline__ u16 f_to_bf16(float f) {
  u32 b = __float_as_uint(f);
  b += 0x7fff + ((b >> 16) & 1);  // round-to-nearest-even
  return (u16)(b >> 16);
}
__device__ __forceinline__ float blo(u32 q) { return __uint_as_float(q << 16); }
__device__ __forceinline__ float bhi(u32 q) {
  return __uint_as_float(q & 0xffff0000u);
}
__device__ __forceinline__ u32 packbf(float lo, float hi) {
  return ((u32)f_to_bf16(hi) << 16) | (u32)f_to_bf16(lo);
}

// ============ prep: cvt_W1 + cvt_W2 + bhist (concurrent sections) =========
__global__ __launch_bounds__(256) void prep_kernel(
    const float* __restrict__ W1, u16* __restrict__ Wt1,
    const float* __restrict__ W2, u16* __restrict__ Wt2,
    const int* __restrict__ ei, int* __restrict__ bcnt, int E_) {
  int blk = blockIdx.x;
  if (blk < 64) {
    int id = blk * 256 + threadIdx.x;  // id = c*128 + k
    Wt1[id] = f_to_bf16(W1[(id & 127) * DIM + (id >> 7)]);
  } else if (blk < 128) {
    int id = (blk - 64) * 256 + threadIdx.x;
    Wt2[id] = f_to_bf16(W2[(id & 127) * DIM + (id >> 7)]);
  } else {
    __shared__ int lc[NBUCK];
    for (int i = threadIdx.x; i < NBUCK; i += 256) lc[i] = 0;
    __syncthreads();
    const int* dst = ei + E_;
    int G = 512 * 256;
    int g = (blk - 128) * 256 + threadIdx.x;
    int n4 = E_ >> 2;
    const int4* d4 = (const int4*)dst;
    for (int i = g; i < n4; i += G) {
      int4 v = d4[i];
      atomicAdd(&lc[((u32)v.x) >> 8], 1);
      atomicAdd(&lc[((u32)v.y) >> 8], 1);
      atomicAdd(&lc[((u32)v.z) >> 8], 1);
      atomicAdd(&lc[((u32)v.w) >> 8], 1);
    }
    for (int e = (n4 << 2) + g; e < E_; e += G)
      atomicAdd(&lc[((u32)dst[e]) >> 8], 1);
    __syncthreads();
    for (int i = threadIdx.x; i < NBUCK; i += 256)
      if (lc[i]) atomicAdd(&bcnt[i], lc[i]);
  }
}

__global__ void bscan_kernel(const int* __restrict__ bcnt,
                             int* __restrict__ boffs, int* __restrict__ gcur) {
  __shared__ int s[256];
  int t = threadIdx.x;
  int v0 = (2 * t < NBUCK) ? bcnt[2 * t] : 0;
  int v1 = (2 * t + 1 < NBUCK) ? bcnt[2 * t + 1] : 0;
  int ts = v0 + v1;
  s[t] = ts;
  __syncthreads();
  for (int o = 1; o < 256; o <<= 1) {
    int u = (t >= o) ? s[t - o] : 0;
    __syncthreads();
    s[t] += u;
    __syncthreads();
  }
  int excl = s[t] - ts;
  if (2 * t <= NBUCK) boffs[2 * t] = excl;
  if (2 * t + 1 <= NBUCK) boffs[2 * t + 1] = excl + v0;
  if (2 * t < NBUCK) gcur[2 * t] = excl;
  if (2 * t + 1 < NBUCK) gcur[2 * t + 1] = excl + v0;
}

// ========= partition (+ concurrent cvt_x in disjoint block range) =========
__global__ __launch_bounds__(PT_THR) void part_cvt_kernel(
    const int* __restrict__ ei, int* __restrict__ gcur,
    u32* __restrict__ packed, int E_, const float* __restrict__ x,
    u16* __restrict__ xb) {
  __shared__ u32 keys[PT_TILE];   // 32 KB
  __shared__ u16 bid[PT_TILE];    // 16 KB
  __shared__ int lh[NBUCK];
  __shared__ int lpos[NBUCK];
  __shared__ int gpos[NBUCK];
  __shared__ int ss[PT_THR];
  const int nPart = (E_ + PT_TILE - 1) / PT_TILE;
  const int t = threadIdx.x;

  if (blockIdx.x >= nPart) {
    // cvt_x section: bf16-convert x with float4/ushort4 streaming
    int cb = blockIdx.x - nPart;  // 0..1023
    int total = N_NODES * DIM / 4;
    int stride = 1024 * PT_THR;
    for (int i = cb * PT_THR + t; i < total; i += stride) {
      float4 v = reinterpret_cast<const float4*>(x)[i];
      ushort4 o;
      o.x = f_to_bf16(v.x);
      o.y = f_to_bf16(v.y);
      o.z = f_to_bf16(v.z);
      o.w = f_to_bf16(v.w);
      reinterpret_cast<ushort4*>(xb)[i] = o;
    }
    return;
  }

  const int base = blockIdx.x * PT_TILE;
  const int cnt = min(PT_TILE, E_ - base);

  for (int i = t; i < NBUCK; i += PT_THR) lh[i] = 0;
  __syncthreads();

  u32 pk[16];
  int bb[16];
#pragma unroll
  for (int k = 0; k < 16; ++k) {
    int e = base + k * PT_THR + t;
    if (k * PT_THR + t < cnt) {
      int src = ei[e];
      u32 dst = (u32)ei[E_ + e];
      bb[k] = (int)(dst >> 8);
      pk[k] = (u32)src | ((dst & 255u) << 17);
      atomicAdd(&lh[bb[k]], 1);
    } else {
      bb[k] = -1;
    }
  }
  __syncthreads();

  int v = (t < NBUCK) ? lh[t] : 0;
  ss[t] = v;
  __syncthreads();
  for (int o = 1; o < PT_THR; o <<= 1) {
    int u = (t >= o) ? ss[t - o] : 0;
    __syncthreads();
    ss[t] += u;
    __syncthreads();
  }
  if (t < NBUCK) {
    lpos[t] = ss[t] - v;
    if (v > 0) gpos[t] = atomicAdd(&gcur[t], v);
  }
  __syncthreads();

#pragma unroll
  for (int k = 0; k < 16; ++k) {
    if (bb[k] >= 0) {
      int p = atomicAdd(&lpos[bb[k]], 1);
      keys[p] = pk[k];
      bid[p] = (u16)bb[k];
    }
  }
  __syncthreads();

  for (int i = t; i < cnt; i += PT_THR) {
    int b = bid[i];
    int startb = lpos[b] - lh[b];
    packed[gpos[b] + (i - startb)] = keys[i];
  }
}

// Per-bucket counting sort in LDS -> exact CSR + per-node offsets.
__global__ __launch_bounds__(256) void bsort_kernel(u32* __restrict__ packed,
                                                    const int* __restrict__ boffs,
                                                    int* __restrict__ offs,
                                                    int E_) {
  __shared__ u32 sorted_[CAP];  // 48 KB
  __shared__ int hist[256], cur[256], ss[256];
  const int b = blockIdx.x, t = threadIdx.x;
  int base = boffs[b];
  int cnt = boffs[b + 1] - base;
  if (cnt > CAP) cnt = CAP;
  hist[t] = 0;
  __syncthreads();
  for (int i = t; i < cnt; i += 256) atomicAdd(&hist[packed[base + i] >> 17], 1);
  __syncthreads();
  int hv = hist[t];
  ss[t] = hv;
  __syncthreads();
  for (int o = 1; o < 256; o <<= 1) {
    int u = (t >= o) ? ss[t - o] : 0;
    __syncthreads();
    ss[t] += u;
    __syncthreads();
  }
  int excl = ss[t] - hv;
  cur[t] = excl;
  __syncthreads();
  for (int i = t; i < cnt; i += 256) {
    u32 v = packed[base + i];
    int p = atomicAdd(&cur[v >> 17], 1);
    sorted_[p] = v & 0x1FFFFu;
  }
  __syncthreads();
  for (int i = t; i < cnt; i += 256) packed[base + i] = sorted_[i];
  int node = b * 256 + t;
  if (node < N_NODES) offs[node] = base + excl;
  if (b == 0 && t == 0) offs[N_NODES] = E_;
}

// ========== Gather v4: 16B/lane loads, 16 lanes/row, 4 edges/wave =========
__global__ __launch_bounds__(256) void gather_bf16_kernel(
    const uint4* __restrict__ xb4, const int* __restrict__ offs,
    const int* __restrict__ csr, uint4* __restrict__ hb4) {
  int n = blockIdx.x * 4 + (threadIdx.x >> 6);
  int lane = threadIdx.x & 63;
  int g = lane >> 4;
  int l = lane & 15;
  int beg = offs[n], end = offs[n + 1];
  float a0 = 0.f, a1 = 0.f, a2 = 0.f, a3 = 0.f;
  float a4 = 0.f, a5 = 0.f, a6 = 0.f, a7 = 0.f;
  if (g == 0) {  // self row
    uint4 q = xb4[(size_t)n * 16 + l];
    a0 = blo(q.x); a1 = bhi(q.x);
    a2 = blo(q.y); a3 = bhi(q.y);
    a4 = blo(q.z); a5 = bhi(q.z);
    a6 = blo(q.w); a7 = bhi(q.w);
  }
  int j = beg + g;
  for (; j + 12 < end; j += 16) {
    int s0 = csr[j], s1 = csr[j + 4], s2 = csr[j + 8], s3 = csr[j + 12];
    uint4 q0 = xb4[(size_t)s0 * 16 + l];
    uint4 q1 = xb4[(size_t)s1 * 16 + l];
    uint4 q2 = xb4[(size_t)s2 * 16 + l];
    uint4 q3 = xb4[(size_t)s3 * 16 + l];
    a0 += blo(q0.x); a1 += bhi(q0.x);
    a2 += blo(q0.y); a3 += bhi(q0.y);
    a4 += blo(q0.z); a5 += bhi(q0.z);
    a6 += blo(q0.w); a7 += bhi(q0.w);
    a0 += blo(q1.x); a1 += bhi(q1.x);
    a2 += blo(q1.y); a3 += bhi(q1.y);
    a4 += blo(q1.z); a5 += bhi(q1.z);
    a6 += blo(q1.w); a7 += bhi(q1.w);
    a0 += blo(q2.x); a1 += bhi(q2.x);
    a2 += blo(q2.y); a3 += bhi(q2.y);
    a4 += blo(q2.z); a5 += bhi(q2.z);
    a6 += blo(q2.w); a7 += bhi(q2.w);
    a0 += blo(q3.x); a1 += bhi(q3.x);
    a2 += blo(q3.y); a3 += bhi(q3.y);
    a4 += blo(q3.z); a5 += bhi(q3.z);
    a6 += blo(q3.w); a7 += bhi(q3.w);
  }
  for (; j < end; j += 4) {
    uint4 q = xb4[(size_t)csr[j] * 16 + l];
    a0 += blo(q.x); a1 += bhi(q.x);
    a2 += blo(q.y); a3 += bhi(q.y);
    a4 += blo(q.z); a5 += bhi(q.z);
    a6 += blo(q.w); a7 += bhi(q.w);
  }
  a0 += __shfl_xor(a0, 16); a1 += __shfl_xor(a1, 16);
  a2 += __shfl_xor(a2, 16); a3 += __shfl_xor(a3, 16);
  a4 += __shfl_xor(a4, 16); a5 += __shfl_xor(a5, 16);
  a6 += __shfl_xor(a6, 16); a7 += __shfl_xor(a7, 16);
  a0 += __shfl_xor(a0, 32); a1 += __shfl_xor(a1, 32);
  a2 += __shfl_xor(a2, 32); a3 += __shfl_xor(a3, 32);
  a4 += __shfl_xor(a4, 32); a5 += __shfl_xor(a5, 32);
  a6 += __shfl_xor(a6, 32); a7 += __shfl_xor(a7, 32);
  if (g == 0) {
    uint4 o;
    o.x = packbf(a0, a1);
    o.y = packbf(a2, a3);
    o.z = packbf(a4, a5);
    o.w = packbf(a6, a7);
    hb4[(size_t)n * 16 + l] = o;
  }
}

// ===== MFMA MLP: bf16 h2 in place in hb + streaming per-block partials ====
__global__ __launch_bounds__(256) void mlp_mfma_kernel(
    u16* __restrict__ hb, const u16* __restrict__ Wt1,
    const u16* __restrict__ Wt2, const float* __restrict__ b1,
    const float* __restrict__ b2, float* __restrict__ pstats) {
  __shared__ u16 sH1[4][16 * DIM];  // 16 KB
  __shared__ float sS[4][128], sQ[4][128];  // 4 KB
  const int tid = threadIdx.x;
  const int wv = tid >> 6;
  const int lane = tid & 63;
  const int lr = lane & 15;
  const int lq = lane >> 4;
  const int row0 = blockIdx.x * 64 + wv * 16;

  // ---- layer 1 ----
  bf16x8 a[4];
  {
    int r = row0 + lr;
    if (r > N_NODES - 1) r = N_NODES - 1;
#pragma unroll
    for (int ks = 0; ks < 4; ++ks)
      a[ks] = *reinterpret_cast<const bf16x8*>(hb + (size_t)r * DIM + ks * 32 +
                                               lq * 8);
  }
  f32x4 acc[8];
#pragma unroll
  for (int ct = 0; ct < 8; ++ct) {
    f32x4 c = {0.f, 0.f, 0.f, 0.f};
#pragma unroll
    for (int ks = 0; ks < 4; ++ks) {
      bf16x8 b = *reinterpret_cast<const bf16x8*>(
          Wt1 + (ct * 16 + lr) * DIM + ks * 32 + lq * 8);
      c = __builtin_amdgcn_mfma_f32_16x16x32_bf16(a[ks], b, c, 0, 0, 0);
    }
    acc[ct] = c;
  }
  char* slab = reinterpret_cast<char*>(&sH1[wv][0]);
#pragma unroll
  for (int ct = 0; ct < 8; ++ct) {
    int c = ct * 16 + lr;
    float bias = b1[c];
#pragma unroll
    for (int j = 0; j < 4; ++j) {
      int rl = lq * 4 + j;
      float y = fmaxf(acc[ct][j] + bias, 0.f);
      int byte = rl * 256 + ((c * 2) ^ ((rl & 7) << 4));
      *reinterpret_cast<u16*>(slab + byte) = f_to_bf16(y);
    }
  }
  __syncthreads();

  // ---- layer 2 ----
  bf16x8 a2[4];
#pragma unroll
  for (int ks = 0; ks < 4; ++ks) {
    int byte = lr * 256 + (((ks * 32 + lq * 8) * 2) ^ ((lr & 7) << 4));
    a2[ks] = *reinterpret_cast<const bf16x8*>(slab + byte);
  }
#pragma unroll
  for (int ct = 0; ct < 8; ++ct) {
    f32x4 c = {0.f, 0.f, 0.f, 0.f};
#pragma unroll
    for (int ks = 0; ks < 4; ++ks) {
      bf16x8 b = *reinterpret_cast<const bf16x8*>(
          Wt2 + (ct * 16 + lr) * DIM + ks * 32 + lq * 8);
      c = __builtin_amdgcn_mfma_f32_16x16x32_bf16(a2[ks], b, c, 0, 0, 0);
    }
    acc[ct] = c;
  }
  // ---- epilogue: bf16 h2 back into hb + per-column (s, ss) of quantized ----
  float ls[8], lss[8];
#pragma unroll
  for (int ct = 0; ct < 8; ++ct) {
    int c = ct * 16 + lr;
    float bias = b2[c];
    ls[ct] = 0.f;
    lss[ct] = 0.f;
#pragma unroll
    for (int j = 0; j < 4; ++j) {
      int r = row0 + lq * 4 + j;
      float y = fmaxf(acc[ct][j] + bias, 0.f);
      u16 yq = f_to_bf16(y);
      float yf = bf16_to_f(yq);
      if (r < N_NODES) {
        hb[(size_t)r * DIM + c] = yq;
        ls[ct] += yf;
        lss[ct] += yf * yf;
      }
    }
  }
#pragma unroll
  for (int ct = 0; ct < 8; ++ct) {
    float s = ls[ct], q = lss[ct];
    s += __shfl_xor(s, 16);
    q += __shfl_xor(q, 16);
    s += __shfl_xor(s, 32);
    q += __shfl_xor(q, 32);
    if (lq == 0) {
      sS[wv][ct * 16 + lr] = s;
      sQ[wv][ct * 16 + lr] = q;
    }
  }
  __syncthreads();
  {
    int t = tid;
    float v;
    if (t < 128)
      v = sS[0][t] + sS[1][t] + sS[2][t] + sS[3][t];
    else
      v = sQ[0][t - 128] + sQ[1][t - 128] + sQ[2][t - 128] + sQ[3][t - 128];
    pstats[(size_t)blockIdx.x * 256 + t] = v;  // streaming, no contention
  }
}

// ======================= BatchNorm =======================
__global__ __launch_bounds__(256) void bn_reduce_kernel(
    const float* __restrict__ pstats, float* __restrict__ stats, int nblk) {
  int t = threadIdx.x;
  float v = 0.f;
  for (int i = blockIdx.x; i < nblk; i += gridDim.x)
    v += pstats[(size_t)i * 256 + t];
  atomicAdd(&stats[t], v);
}

// ======= BN apply: per-block scale/shift from stats, bf16 in, f32 out =====
__global__ __launch_bounds__(256) void bn_apply_bf16_kernel(
    const uint4* __restrict__ hb4, const float* __restrict__ stats,
    const float* __restrict__ gamma, const float* __restrict__ beta,
    float4* __restrict__ out4) {
  __shared__ float sSc[128], sSh[128];
  int t = threadIdx.x;
  if (t < 128) {
    float mean = stats[t] / (float)N_NODES;
    float var = stats[128 + t] / (float)N_NODES - mean * mean;
    float scale = gamma[t] * rsqrtf(var + 1e-5f);
    sSc[t] = scale;
    sSh[t] = beta[t] - mean * scale;
  }
  __syncthreads();
  int total = N_NODES * 16;  // uint4 per row of 128 bf16
  int stride = gridDim.x * 256;
  for (int i = blockIdx.x * 256 + t; i < total; i += stride) {
    uint4 q = hb4[i];
    int cb = (i & 15) * 8;
    float4 o0, o1;
    o0.x = blo(q.x) * sSc[cb + 0] + sSh[cb + 0];
    o0.y = bhi(q.x) * sSc[cb + 1] + sSh[cb + 1];
    o0.z = blo(q.y) * sSc[cb + 2] + sSh[cb + 2];
    o0.w = bhi(q.y) * sSc[cb + 3] + sSh[cb + 3];
    o1.x = blo(q.z) * sSc[cb + 4] + sSh[cb + 4];
    o1.y = bhi(q.z) * sSc[cb + 5] + sSh[cb + 5];
    o1.z = blo(q.w) * sSc[cb + 6] + sSh[cb + 6];
    o1.w = bhi(q.w) * sSc[cb + 7] + sSh[cb + 7];
    out4[2 * i] = o0;
    out4[2 * i + 1] = o1;
  }
}

// ======================= Fallback kernels =======================
__global__ __launch_bounds__(256) void hist_kernel(const int* __restrict__ ei,
                                                   int* __restrict__ deg,
                                                   int E_) {
  int stride = gridDim.x * blockDim.x;
  for (int e = blockIdx.x * blockDim.x + threadIdx.x; e < E_; e += stride)
    atomicAdd(&deg[ei[E_ + e]], 1);
}

__global__ __launch_bounds__(256) void scan_block_kernel(
    const int* __restrict__ deg, int* __restrict__ offs,
    int* __restrict__ partials, int n) {
  const int tid = threadIdx.x;
  int g = blockIdx.x * 1024 + tid * 4;
  int v0 = (g + 0 < n) ? deg[g + 0] : 0;
  int v1 = (g + 1 < n) ? deg[g + 1] : 0;
  int v2 = (g + 2 < n) ? deg[g + 2] : 0;
  int v3 = (g + 3 < n) ? deg[g + 3] : 0;
  int tsum = v0 + v1 + v2 + v3;
  __shared__ int s[256];
  s[tid] = tsum;
  __syncthreads();
  for (int off = 1; off < 256; off <<= 1) {
    int t = (tid >= off) ? s[tid - off] : 0;
    __syncthreads();
    s[tid] += t;
    __syncthreads();
  }
  int excl = s[tid] - tsum;
  if (g + 0 < n) offs[g + 0] = excl;
  if (g + 1 < n) offs[g + 1] = excl + v0;
  if (g + 2 < n) offs[g + 2] = excl + v0 + v1;
  if (g + 3 < n) offs[g + 3] = excl + v0 + v1 + v2;
  if (tid == 255) partials[blockIdx.x] = s[255];
}

__global__ void scan_partials_kernel(int* __restrict__ partials, int nb) {
  const int tid = threadIdx.x;
  int v = (tid < nb) ? partials[tid] : 0;
  __shared__ int s[128];
  s[tid] = v;
  __syncthreads();
  for (int off = 1; off < 128; off <<= 1) {
    int t = (tid >= off) ? s[tid - off] : 0;
    __syncthreads();
    s[tid] += t;
    __syncthreads();
  }
  if (tid < nb) partials[tid] = s[tid] - v;
}

__global__ __launch_bounds__(256) void scan_add_kernel(
    int* __restrict__ offs, int* __restrict__ cursor,
    const int* __restrict__ partials, int n, int E_) {
  int g = blockIdx.x * blockDim.x + threadIdx.x;
  if (g < n) {
    int v = offs[g] + partials[g >> 10];
    offs[g] = v;
    cursor[g] = v;
  }
  if (g == 0) offs[n] = E_;
}

__global__ __launch_bounds__(256) void fill_kernel(const int* __restrict__ ei,
                                                   int* __restrict__ cursor,
                                                   int* __restrict__ csr,
                                                   int E_) {
  const int G = gridDim.x * blockDim.x;
  int g = blockIdx.x * blockDim.x + threadIdx.x;
  for (long long base = g; base < E_; base += (long long)G * 8) {
    int src[8], dst[8], pos[8];
#pragma unroll
    for (int k = 0; k < 8; ++k) {
      long long e = base + (long long)k * G;
      src[k] = (e < E_) ? ei[e] : -1;
      dst[k] = (e < E_) ? ei[E_ + e] : 0;
    }
#pragma unroll
    for (int k = 0; k < 8; ++k)
      if (src[k] >= 0) pos[k] = atomicAdd(&cursor[dst[k]], 1);
#pragma unroll
    for (int k = 0; k < 8; ++k)
      if (src[k] >= 0) csr[pos[k]] = src[k];
  }
}

__global__ __launch_bounds__(128) void gather_f32_kernel(
    const float* __restrict__ x, const int* __restrict__ offs,
    const int* __restrict__ csr, float* __restrict__ h) {
  int n = blockIdx.x;
  int c = threadIdx.x;
  int beg = offs[n], end = offs[n + 1];
  float acc = x[(size_t)n * DIM + c];
  for (int j = beg; j < end; ++j) acc += x[(size_t)csr[j] * DIM + c];
  h[(size_t)n * DIM + c] = acc;
}

__global__ __launch_bounds__(256) void scatter_kernel(
    const float* __restrict__ x, const int* __restrict__ ei,
    float* __restrict__ h, int E_) {
  long long total = (long long)E_ * 32;
  long long stride = (long long)gridDim.x * blockDim.x;
  for (long long idx = (long long)blockIdx.x * blockDim.x + threadIdx.x;
       idx < total; idx += stride) {
    int e = (int)(idx >> 5);
    int q = (int)(idx & 31);
    float4 v =
        *reinterpret_cast<const float4*>(x + (size_t)ei[e] * DIM + q * 4);
    float* p = h + (size_t)ei[E_ + e] * DIM + q * 4;
    atomicAdd(p + 0, v.x);
    atomicAdd(p + 1, v.y);
    atomicAdd(p + 2, v.z);
    atomicAdd(p + 3, v.w);
  }
}

__global__ __launch_bounds__(256) void add_x_kernel(const float* __restrict__ x,
                                                    float* __restrict__ h) {
  size_t total = (size_t)N_NODES * DIM / 4;
  size_t stride = (size_t)gridDim.x * blockDim.x;
  for (size_t i = (size_t)blockIdx.x * blockDim.x + threadIdx.x; i < total;
       i += stride) {
    float4 v = reinterpret_cast<float4*>(h)[i];
    float4 xv = reinterpret_cast<const float4*>(x)[i];
    v.x += xv.x; v.y += xv.y; v.z += xv.z; v.w += xv.w;
    reinterpret_cast<float4*>(h)[i] = v;
  }
}

__global__ __launch_bounds__(256) void mlp_valu_kernel(
    float* hbuf, const float* __restrict__ W1, const float* __restrict__ b1,
    const float* __restrict__ W2, const float* __restrict__ b2) {
  __shared__ float sW[DIM * DIM];
  __shared__ float sH[32][DIM];
  const int tid = threadIdx.x;
  const int col = tid & 127;
  const int rhalf = tid >> 7;
  const int row0 = blockIdx.x * 32;

  for (int i = tid; i < DIM * DIM; i += 256) sW[i] = W1[i];
  for (int i = tid; i < 32 * DIM; i += 256) {
    int r = i >> 7, c = i & 127;
    sH[r][c] = hbuf[(size_t)(row0 + r) * DIM + c];
  }
  __syncthreads();
  float acc[16];
  float bias = b1[col];
#pragma unroll
  for (int j = 0; j < 16; ++j) acc[j] = bias;
#pragma unroll 4
  for (int k = 0; k < DIM; ++k) {
    float w = sW[k * DIM + col];
#pragma unroll
    for (int j = 0; j < 16; ++j) acc[j] = fmaf(sH[2 * j + rhalf][k], w, acc[j]);
  }
  __syncthreads();
  for (int i = tid; i < DIM * DIM; i += 256) sW[i] = W2[i];
#pragma unroll
  for (int j = 0; j < 16; ++j) sH[2 * j + rhalf][col] = fmaxf(acc[j], 0.f);
  __syncthreads();
  float bias2 = b2[col];
#pragma unroll
  for (int j = 0; j < 16; ++j) acc[j] = bias2;
#pragma unroll 4
  for (int k = 0; k < DIM; ++k) {
    float w = sW[k * DIM + col];
#pragma unroll
    for (int j = 0; j < 16; ++j) acc[j] = fmaf(sH[2 * j + rhalf][k], w, acc[j]);
  }
#pragma unroll
  for (int j = 0; j < 16; ++j)
    hbuf[(size_t)(row0 + 2 * j + rhalf) * DIM + col] = fmaxf(acc[j], 0.f);
}

__global__ __launch_bounds__(256) void bn_stats_kernel(
    const float* __restrict__ h, float* __restrict__ stats) {
  int col = threadIdx.x & 127;
  int rsub = threadIdx.x >> 7;
  int rstep = gridDim.x * 2;
  float s = 0.f, ss = 0.f;
  for (int r = blockIdx.x * 2 + rsub; r < N_NODES; r += rstep) {
    float v = h[(size_t)r * DIM + col];
    s += v;
    ss += v * v;
  }
  __shared__ float ls[256], lss[256];
  ls[threadIdx.x] = s;
  lss[threadIdx.x] = ss;
  __syncthreads();
  if (threadIdx.x < 128) {
    atomicAdd(&stats[col], ls[threadIdx.x] + ls[threadIdx.x + 128]);
    atomicAdd(&stats[DIM + col], lss[threadIdx.x] + lss[threadIdx.x + 128]);
  }
}

__global__ void bn_scale_kernel(const float* __restrict__ stats,
                                const float* __restrict__ gamma,
                                const float* __restrict__ beta,
                                float* __restrict__ sc) {
  int c = threadIdx.x;  // 128
  float mean = stats[c] / (float)N_NODES;
  float var = stats[DIM + c] / (float)N_NODES - mean * mean;
  float scale = gamma[c] * rsqrtf(var + 1e-5f);
  sc[c] = scale;
  sc[DIM + c] = beta[c] - mean * scale;
}

__global__ __launch_bounds__(256) void bn_apply_kernel(
    float* __restrict__ h, const float* __restrict__ sc) {
  size_t total = (size_t)N_NODES * DIM / 4;
  size_t stride = (size_t)gridDim.x * blockDim.x;
  for (size_t i = (size_t)blockIdx.x * blockDim.x + threadIdx.x; i < total;
       i += stride) {
    float4 v = reinterpret_cast<float4*>(h)[i];
    int c = (int)((i * 4) & 127);
    v.x = v.x * sc[c + 0] + sc[DIM + c + 0];
    v.y = v.y * sc[c + 1] + sc[DIM + c + 1];
    v.z = v.z * sc[c + 2] + sc[DIM + c + 2];
    v.w = v.w * sc[c + 3] + sc[DIM + c + 3];
    reinterpret_cast<float4*>(h)[i] = v;
  }
}

extern "C" void kernel_launch(void* const* d_in, const int* in_sizes, int n_in,
                              void* d_out, int out_size, void* d_ws,
                              size_t ws_size, hipStream_t stream) {
  const float* x = (const float*)d_in[0];
  const int* ei = (const int*)d_in[1];
  const float* W1 = (const float*)d_in[3];
  const float* b1 = (const float*)d_in[4];
  const float* W2 = (const float*)d_in[5];
  const float* b2 = (const float*)d_in[6];
  const float* gamma = (const float*)d_in[7];
  const float* beta = (const float*)d_in[8];
  float* out = (float*)d_out;
  int E_ = in_sizes[1] / 2;

  // ---- full-path workspace layout (16B-aligned fields) ----
  const size_t XB_B = (size_t)N_NODES * DIM * 2;  // 25.6e6
  char* w = (char*)d_ws;
  size_t off = 0;
  u16* xb = (u16*)(w + off); off += XB_B;
  u16* hb = (u16*)(w + off); off += XB_B;
  u16* Wt1 = (u16*)(w + off); off += 32768;
  u16* Wt2 = (u16*)(w + off); off += 32768;
  u32* packed = (u32*)(w + off); off += (size_t)E_ * 4;      // doubles as csr
  int* offs = (int*)(w + off); off += ((size_t)N_NODES + 4) * 4;
  int* bcnt = (int*)(w + off); off += 1600;
  float* stats = (float*)(w + off); off += 3072;
  int* boffs = (int*)(w + off); off += 1600;
  int* gcur = (int*)(w + off); off += 1600;
  size_t need_full = off;
  float* pstats = (float*)xb;  // xb is dead after gather

  // ---- CSR-only fallback layout ----
  int* f_offs = (int*)d_ws;
  int* f_cursor = f_offs + N_NODES + 1;
  int* f_partials = f_cursor + N_NODES;
  int* f_csr = f_partials + 128;
  float* f_stats = (float*)(f_csr + E_);
  size_t need_csr = ((size_t)2 * N_NODES + 129 + E_) * 4 + 3072;

  const int nScanBlocks = (N_NODES + 1023) / 1024;  // 98
  const int nEdgeBlocks = (E_ + 2047) / 2048;
  const int nPartBlocks = (E_ + PT_TILE - 1) / PT_TILE;
  const int nMlpBlocks = (N_NODES + 63) / 64;  // 1563

  if (ws_size >= need_full) {
    hipMemsetAsync(bcnt, 0, 1600 + 3072, stream);  // bcnt + stats
    prep_kernel<<<640, 256, 0, stream>>>(W1, Wt1, W2, Wt2, ei, bcnt, E_);
    bscan_kernel<<<1, 256, 0, stream>>>(bcnt, boffs, gcur);
    part_cvt_kernel<<<nPartBlocks + 1024, PT_THR, 0, stream>>>(
        ei, gcur, packed, E_, x, xb);
    bsort_kernel<<<NBUCK, 256, 0, stream>>>(packed, boffs, offs, E_);
    gather_bf16_kernel<<<N_NODES / 4, 256, 0, stream>>>(
        (const uint4*)xb, offs, (const int*)packed, (uint4*)hb);
    mlp_mfma_kernel<<<nMlpBlocks, 256, 0, stream>>>(hb, Wt1, Wt2, b1, b2,
                                                    pstats);
    bn_reduce_kernel<<<32, 256, 0, stream>>>(pstats, stats, nMlpBlocks);
    bn_apply_bf16_kernel<<<2048, 256, 0, stream>>>(
        (const uint4*)hb, stats, gamma, beta, (float4*)out);
  } else if (ws_size >= need_csr) {
    hipMemsetAsync(f_cursor, 0, (size_t)N_NODES * sizeof(int), stream);
    hipMemsetAsync(f_stats, 0, 768 * sizeof(float), stream);
    hist_kernel<<<2048, 256, 0, stream>>>(ei, f_cursor, E_);
    scan_block_kernel<<<nScanBlocks, 256, 0, stream>>>(f_cursor, f_offs,
                                                       f_partials, N_NODES);
    scan_partials_kernel<<<1, 128, 0, stream>>>(f_partials, nScanBlocks);
    scan_add_kernel<<<(N_NODES + 255) / 256, 256, 0, stream>>>(
        f_offs, f_cursor, f_partials, N_NODES, E_);
    fill_kernel<<<nEdgeBlocks, 256, 0, stream>>>(ei, f_cursor, f_csr, E_);
    gather_f32_kernel<<<N_NODES, 128, 0, stream>>>(x, f_offs, f_csr, out);
    mlp_valu_kernel<<<(N_NODES + 31) / 32, 256, 0, stream>>>(out, W1, b1, W2,
                                                             b2);
    bn_stats_kernel<<<1024, 256, 0, stream>>>(out, f_stats);
    bn_scale_kernel<<<1, 128, 0, stream>>>(f_stats, gamma, beta, f_stats + 256);
    bn_apply_kernel<<<2048, 256, 0, stream>>>(out, f_stats + 256);
  } else {
    float* s2 = (float*)d_ws;
    hipMemsetAsync(out, 0, (size_t)N_NODES * DIM * sizeof(float), stream);
    hipMemsetAsync(s2, 0, 768 * sizeof(float), stream);
    scatter_kernel<<<4096, 256, 0, stream>>>(x, ei, out, E_);
    add_x_kernel<<<2048, 256, 0, stream>>>(x, out);
    mlp_valu_kernel<<<(N_NODES + 31) / 32, 256, 0, stream>>>(out, W1, b1, W2,
                                                             b2);
    bn_stats_kernel<<<1024, 256, 0, stream>>>(out, s2);
    bn_scale_kernel<<<1, 128, 0, stream>>>(s2, gamma, beta, s2 + 256);
    bn_apply_kernel<<<2048, 256, 0, stream>>>(out, s2 + 256);
  }
}

// Round 12
// 259.503 us; speedup vs baseline: 1.1148x; 1.0650x over previous
//
#include <hip/hip_runtime.h>

#define N_NODES 100000
#define DIM 128
#define NBUCK 391    // ceil(N/256), bucket = dst>>8 (256 nodes per bucket)
#define CAP 12288    // max edges per bucket (mean 8187, +45 sigma)
#define PT_TILE 8192 // edges per partition block
#define PT_THR 512

typedef unsigned int u32;
typedef unsigned short u16;
typedef __attribute__((ext_vector_type(8))) short bf16x8;
typedef __attribute__((ext_vector_type(4))) float f32x4;

__device__ __forceinline__ float bf16_to_f(u16 v) {
  return __uint_as_float(((u32)v) << 16);
}
__device__ __forceinline__ u16 f_to_bf16(float f) {
  u32 b = __float_as_uint(f);
  b += 0x7fff + ((b >> 16) & 1);  // round-to-nearest-even
  return (u16)(b >> 16);
}
__device__ __forceinline__ float blo(u32 q) { return __uint_as_float(q << 16); }
__device__ __forceinline__ float bhi(u32 q) {
  return __uint_as_float(q & 0xffff0000u);
}
__device__ __forceinline__ u32 packbf(float lo, float hi) {
  return ((u32)f_to_bf16(hi) << 16) | (u32)f_to_bf16(lo);
}

// ============ prep: cvt_W1 + cvt_W2 + bhist (concurrent sections) =========
__global__ __launch_bounds__(256) void prep_kernel(
    const float* __restrict__ W1, u16* __restrict__ Wt1,
    const float* __restrict__ W2, u16* __restrict__ Wt2,
    const int* __restrict__ ei, int* __restrict__ bcnt, int E_) {
  int blk = blockIdx.x;
  if (blk < 64) {
    int id = blk * 256 + threadIdx.x;  // id = c*128 + k
    Wt1[id] = f_to_bf16(W1[(id & 127) * DIM + (id >> 7)]);
  } else if (blk < 128) {
    int id = (blk - 64) * 256 + threadIdx.x;
    Wt2[id] = f_to_bf16(W2[(id & 127) * DIM + (id >> 7)]);
  } else {
    __shared__ int lc[NBUCK];
    for (int i = threadIdx.x; i < NBUCK; i += 256) lc[i] = 0;
    __syncthreads();
    const int* dst = ei + E_;
    int G = 512 * 256;
    int g = (blk - 128) * 256 + threadIdx.x;
    int n4 = E_ >> 2;
    const int4* d4 = (const int4*)dst;
    for (int i = g; i < n4; i += G) {
      int4 v = d4[i];
      atomicAdd(&lc[((u32)v.x) >> 8], 1);
      atomicAdd(&lc[((u32)v.y) >> 8], 1);
      atomicAdd(&lc[((u32)v.z) >> 8], 1);
      atomicAdd(&lc[((u32)v.w) >> 8], 1);
    }
    for (int e = (n4 << 2) + g; e < E_; e += G)
      atomicAdd(&lc[((u32)dst[e]) >> 8], 1);
    __syncthreads();
    for (int i = threadIdx.x; i < NBUCK; i += 256)
      if (lc[i]) atomicAdd(&bcnt[i], lc[i]);
  }
}

__global__ void bscan_kernel(const int* __restrict__ bcnt,
                             int* __restrict__ boffs, int* __restrict__ gcur) {
  __shared__ int s[256];
  int t = threadIdx.x;
  int v0 = (2 * t < NBUCK) ? bcnt[2 * t] : 0;
  int v1 = (2 * t + 1 < NBUCK) ? bcnt[2 * t + 1] : 0;
  int ts = v0 + v1;
  s[t] = ts;
  __syncthreads();
  for (int o = 1; o < 256; o <<= 1) {
    int u = (t >= o) ? s[t - o] : 0;
    __syncthreads();
    s[t] += u;
    __syncthreads();
  }
  int excl = s[t] - ts;
  if (2 * t <= NBUCK) boffs[2 * t] = excl;
  if (2 * t + 1 <= NBUCK) boffs[2 * t + 1] = excl + v0;
  if (2 * t < NBUCK) gcur[2 * t] = excl;
  if (2 * t + 1 < NBUCK) gcur[2 * t + 1] = excl + v0;
}

// ========= partition (+ concurrent cvt_x in disjoint block range) =========
__global__ __launch_bounds__(PT_THR) void part_cvt_kernel(
    const int* __restrict__ ei, int* __restrict__ gcur,
    u32* __restrict__ packed, int E_, const float* __restrict__ x,
    u16* __restrict__ xb) {
  __shared__ u32 keys[PT_TILE];   // 32 KB
  __shared__ u16 bid[PT_TILE];    // 16 KB
  __shared__ int lh[NBUCK];
  __shared__ int lpos[NBUCK];
  __shared__ int gpos[NBUCK];
  __shared__ int ss[PT_THR];
  const int nPart = (E_ + PT_TILE - 1) / PT_TILE;
  const int t = threadIdx.x;

  if (blockIdx.x >= nPart) {
    int cb = blockIdx.x - nPart;  // 0..1023
    int total = N_NODES * DIM / 4;
    int stride = 1024 * PT_THR;
    for (int i = cb * PT_THR + t; i < total; i += stride) {
      float4 v = reinterpret_cast<const float4*>(x)[i];
      ushort4 o;
      o.x = f_to_bf16(v.x);
      o.y = f_to_bf16(v.y);
      o.z = f_to_bf16(v.z);
      o.w = f_to_bf16(v.w);
      reinterpret_cast<ushort4*>(xb)[i] = o;
    }
    return;
  }

  const int base = blockIdx.x * PT_TILE;
  const int cnt = min(PT_TILE, E_ - base);

  for (int i = t; i < NBUCK; i += PT_THR) lh[i] = 0;
  __syncthreads();

  u32 pk[16];
  int bb[16];
#pragma unroll
  for (int k = 0; k < 16; ++k) {
    int e = base + k * PT_THR + t;
    if (k * PT_THR + t < cnt) {
      int src = ei[e];
      u32 dst = (u32)ei[E_ + e];
      bb[k] = (int)(dst >> 8);
      pk[k] = (u32)src | ((dst & 255u) << 17);
      atomicAdd(&lh[bb[k]], 1);
    } else {
      bb[k] = -1;
    }
  }
  __syncthreads();

  int v = (t < NBUCK) ? lh[t] : 0;
  ss[t] = v;
  __syncthreads();
  for (int o = 1; o < PT_THR; o <<= 1) {
    int u = (t >= o) ? ss[t - o] : 0;
    __syncthreads();
    ss[t] += u;
    __syncthreads();
  }
  if (t < NBUCK) {
    lpos[t] = ss[t] - v;
    if (v > 0) gpos[t] = atomicAdd(&gcur[t], v);
  }
  __syncthreads();

#pragma unroll
  for (int k = 0; k < 16; ++k) {
    if (bb[k] >= 0) {
      int p = atomicAdd(&lpos[bb[k]], 1);
      keys[p] = pk[k];
      bid[p] = (u16)bb[k];
    }
  }
  __syncthreads();

  for (int i = t; i < cnt; i += PT_THR) {
    int b = bid[i];
    int startb = lpos[b] - lh[b];
    packed[gpos[b] + (i - startb)] = keys[i];
  }
}

// ===== Fused bucket-sort + gather: one 1024-thread block per bucket =======
// Phase 1: counting-sort the bucket's edges in LDS (single global read).
// Phase 2: 16 waves x 16 nodes each run the v4 gather loop with neighbor
//          indices served from LDS; 16B/lane row loads; shfl reduce.
__global__ __launch_bounds__(1024) void sortgather_kernel(
    const u32* __restrict__ packed, const int* __restrict__ boffs,
    const uint4* __restrict__ xb4, uint4* __restrict__ hb4) {
  __shared__ u32 sorted_[CAP];   // 48 KB: srcs grouped by node
  __shared__ int hist[256], cur[256], ssc[256];
  __shared__ int nodeoff[257];
  const int b = blockIdx.x;
  const int t = threadIdx.x;
  int base = boffs[b];
  int cnt = boffs[b + 1] - base;
  if (cnt > CAP) cnt = CAP;  // statistically unreachable guard

  if (t < 256) hist[t] = 0;
  __syncthreads();
  for (int i = t; i < cnt; i += 1024)
    atomicAdd(&hist[packed[base + i] >> 17], 1);
  __syncthreads();
  if (t < 256) ssc[t] = hist[t];
  __syncthreads();
  for (int o = 1; o < 256; o <<= 1) {
    int u = 0;
    if (t < 256 && t >= o) u = ssc[t - o];
    __syncthreads();
    if (t < 256) ssc[t] += u;
    __syncthreads();
  }
  if (t < 256) {
    int excl = ssc[t] - hist[t];
    cur[t] = excl;
    nodeoff[t] = excl;
  }
  if (t == 0) nodeoff[256] = cnt;
  __syncthreads();
  for (int i = t; i < cnt; i += 1024) {
    u32 v = packed[base + i];
    int p = atomicAdd(&cur[v >> 17], 1);
    sorted_[p] = v & 0x1FFFFu;
  }
  __syncthreads();

  // ---- gather phase ----
  const int wv = t >> 6;       // 0..15
  const int lane = t & 63;
  const int g = lane >> 4;     // 4 groups of 16 lanes
  const int l = lane & 15;
#pragma unroll 1
  for (int k = 0; k < 16; ++k) {
    int nl = wv + (k << 4);    // node-local 0..255
    int n = b * 256 + nl;
    if (n >= N_NODES) break;
    int beg = nodeoff[nl], end = nodeoff[nl + 1];
    float a0 = 0.f, a1 = 0.f, a2 = 0.f, a3 = 0.f;
    float a4 = 0.f, a5 = 0.f, a6 = 0.f, a7 = 0.f;
    if (g == 0) {  // self row
      uint4 q = xb4[(size_t)n * 16 + l];
      a0 = blo(q.x); a1 = bhi(q.x);
      a2 = blo(q.y); a3 = bhi(q.y);
      a4 = blo(q.z); a5 = bhi(q.z);
      a6 = blo(q.w); a7 = bhi(q.w);
    }
    int j = beg + g;
    for (; j + 12 < end; j += 16) {
      int s0 = sorted_[j], s1 = sorted_[j + 4];
      int s2 = sorted_[j + 8], s3 = sorted_[j + 12];
      uint4 q0 = xb4[(size_t)s0 * 16 + l];
      uint4 q1 = xb4[(size_t)s1 * 16 + l];
      uint4 q2 = xb4[(size_t)s2 * 16 + l];
      uint4 q3 = xb4[(size_t)s3 * 16 + l];
      a0 += blo(q0.x); a1 += bhi(q0.x);
      a2 += blo(q0.y); a3 += bhi(q0.y);
      a4 += blo(q0.z); a5 += bhi(q0.z);
      a6 += blo(q0.w); a7 += bhi(q0.w);
      a0 += blo(q1.x); a1 += bhi(q1.x);
      a2 += blo(q1.y); a3 += bhi(q1.y);
      a4 += blo(q1.z); a5 += bhi(q1.z);
      a6 += blo(q1.w); a7 += bhi(q1.w);
      a0 += blo(q2.x); a1 += bhi(q2.x);
      a2 += blo(q2.y); a3 += bhi(q2.y);
      a4 += blo(q2.z); a5 += bhi(q2.z);
      a6 += blo(q2.w); a7 += bhi(q2.w);
      a0 += blo(q3.x); a1 += bhi(q3.x);
      a2 += blo(q3.y); a3 += bhi(q3.y);
      a4 += blo(q3.z); a5 += bhi(q3.z);
      a6 += blo(q3.w); a7 += bhi(q3.w);
    }
    for (; j < end; j += 4) {
      uint4 q = xb4[(size_t)sorted_[j] * 16 + l];
      a0 += blo(q.x); a1 += bhi(q.x);
      a2 += blo(q.y); a3 += bhi(q.y);
      a4 += blo(q.z); a5 += bhi(q.z);
      a6 += blo(q.w); a7 += bhi(q.w);
    }
    a0 += __shfl_xor(a0, 16); a1 += __shfl_xor(a1, 16);
    a2 += __shfl_xor(a2, 16); a3 += __shfl_xor(a3, 16);
    a4 += __shfl_xor(a4, 16); a5 += __shfl_xor(a5, 16);
    a6 += __shfl_xor(a6, 16); a7 += __shfl_xor(a7, 16);
    a0 += __shfl_xor(a0, 32); a1 += __shfl_xor(a1, 32);
    a2 += __shfl_xor(a2, 32); a3 += __shfl_xor(a3, 32);
    a4 += __shfl_xor(a4, 32); a5 += __shfl_xor(a5, 32);
    a6 += __shfl_xor(a6, 32); a7 += __shfl_xor(a7, 32);
    if (g == 0) {
      uint4 o;
      o.x = packbf(a0, a1);
      o.y = packbf(a2, a3);
      o.z = packbf(a4, a5);
      o.w = packbf(a6, a7);
      hb4[(size_t)n * 16 + l] = o;
    }
  }
}

// ===== MFMA MLP: bf16 h2 in place in hb + streaming per-block partials ====
__global__ __launch_bounds__(256) void mlp_mfma_kernel(
    u16* __restrict__ hb, const u16* __restrict__ Wt1,
    const u16* __restrict__ Wt2, const float* __restrict__ b1,
    const float* __restrict__ b2, float* __restrict__ pstats) {
  __shared__ u16 sH1[4][16 * DIM];  // 16 KB
  __shared__ float sS[4][128], sQ[4][128];  // 4 KB
  const int tid = threadIdx.x;
  const int wv = tid >> 6;
  const int lane = tid & 63;
  const int lr = lane & 15;
  const int lq = lane >> 4;
  const int row0 = blockIdx.x * 64 + wv * 16;

  // ---- layer 1 ----
  bf16x8 a[4];
  {
    int r = row0 + lr;
    if (r > N_NODES - 1) r = N_NODES - 1;
#pragma unroll
    for (int ks = 0; ks < 4; ++ks)
      a[ks] = *reinterpret_cast<const bf16x8*>(hb + (size_t)r * DIM + ks * 32 +
                                               lq * 8);
  }
  f32x4 acc[8];
#pragma unroll
  for (int ct = 0; ct < 8; ++ct) {
    f32x4 c = {0.f, 0.f, 0.f, 0.f};
#pragma unroll
    for (int ks = 0; ks < 4; ++ks) {
      bf16x8 b = *reinterpret_cast<const bf16x8*>(
          Wt1 + (ct * 16 + lr) * DIM + ks * 32 + lq * 8);
      c = __builtin_amdgcn_mfma_f32_16x16x32_bf16(a[ks], b, c, 0, 0, 0);
    }
    acc[ct] = c;
  }
  char* slab = reinterpret_cast<char*>(&sH1[wv][0]);
#pragma unroll
  for (int ct = 0; ct < 8; ++ct) {
    int c = ct * 16 + lr;
    float bias = b1[c];
#pragma unroll
    for (int j = 0; j < 4; ++j) {
      int rl = lq * 4 + j;
      float y = fmaxf(acc[ct][j] + bias, 0.f);
      int byte = rl * 256 + ((c * 2) ^ ((rl & 7) << 4));
      *reinterpret_cast<u16*>(slab + byte) = f_to_bf16(y);
    }
  }
  __syncthreads();

  // ---- layer 2 ----
  bf16x8 a2[4];
#pragma unroll
  for (int ks = 0; ks < 4; ++ks) {
    int byte = lr * 256 + (((ks * 32 + lq * 8) * 2) ^ ((lr & 7) << 4));
    a2[ks] = *reinterpret_cast<const bf16x8*>(slab + byte);
  }
#pragma unroll
  for (int ct = 0; ct < 8; ++ct) {
    f32x4 c = {0.f, 0.f, 0.f, 0.f};
#pragma unroll
    for (int ks = 0; ks < 4; ++ks) {
      bf16x8 b = *reinterpret_cast<const bf16x8*>(
          Wt2 + (ct * 16 + lr) * DIM + ks * 32 + lq * 8);
      c = __builtin_amdgcn_mfma_f32_16x16x32_bf16(a2[ks], b, c, 0, 0, 0);
    }
    acc[ct] = c;
  }
  // ---- epilogue: bf16 h2 back into hb + per-column (s, ss) of quantized ----
  float ls[8], lss[8];
#pragma unroll
  for (int ct = 0; ct < 8; ++ct) {
    int c = ct * 16 + lr;
    float bias = b2[c];
    ls[ct] = 0.f;
    lss[ct] = 0.f;
#pragma unroll
    for (int j = 0; j < 4; ++j) {
      int r = row0 + lq * 4 + j;
      float y = fmaxf(acc[ct][j] + bias, 0.f);
      u16 yq = f_to_bf16(y);
      float yf = bf16_to_f(yq);
      if (r < N_NODES) {
        hb[(size_t)r * DIM + c] = yq;
        ls[ct] += yf;
        lss[ct] += yf * yf;
      }
    }
  }
#pragma unroll
  for (int ct = 0; ct < 8; ++ct) {
    float s = ls[ct], q = lss[ct];
    s += __shfl_xor(s, 16);
    q += __shfl_xor(q, 16);
    s += __shfl_xor(s, 32);
    q += __shfl_xor(q, 32);
    if (lq == 0) {
      sS[wv][ct * 16 + lr] = s;
      sQ[wv][ct * 16 + lr] = q;
    }
  }
  __syncthreads();
  {
    int t = tid;
    float v;
    if (t < 128)
      v = sS[0][t] + sS[1][t] + sS[2][t] + sS[3][t];
    else
      v = sQ[0][t - 128] + sQ[1][t - 128] + sQ[2][t - 128] + sQ[3][t - 128];
    pstats[(size_t)blockIdx.x * 256 + t] = v;  // streaming, no contention
  }
}

// ======================= BatchNorm =======================
__global__ __launch_bounds__(256) void bn_reduce_kernel(
    const float* __restrict__ pstats, float* __restrict__ stats, int nblk) {
  int t = threadIdx.x;
  float v = 0.f;
  for (int i = blockIdx.x; i < nblk; i += gridDim.x)
    v += pstats[(size_t)i * 256 + t];
  atomicAdd(&stats[t], v);
}

__global__ __launch_bounds__(256) void bn_apply_bf16_kernel(
    const uint4* __restrict__ hb4, const float* __restrict__ stats,
    const float* __restrict__ gamma, const float* __restrict__ beta,
    float4* __restrict__ out4) {
  __shared__ float sSc[128], sSh[128];
  int t = threadIdx.x;
  if (t < 128) {
    float mean = stats[t] / (float)N_NODES;
    float var = stats[128 + t] / (float)N_NODES - mean * mean;
    float scale = gamma[t] * rsqrtf(var + 1e-5f);
    sSc[t] = scale;
    sSh[t] = beta[t] - mean * scale;
  }
  __syncthreads();
  int total = N_NODES * 16;  // uint4 per row of 128 bf16
  int stride = gridDim.x * 256;
  for (int i = blockIdx.x * 256 + t; i < total; i += stride) {
    uint4 q = hb4[i];
    int cb = (i & 15) * 8;
    float4 o0, o1;
    o0.x = blo(q.x) * sSc[cb + 0] + sSh[cb + 0];
    o0.y = bhi(q.x) * sSc[cb + 1] + sSh[cb + 1];
    o0.z = blo(q.y) * sSc[cb + 2] + sSh[cb + 2];
    o0.w = bhi(q.y) * sSc[cb + 3] + sSh[cb + 3];
    o1.x = blo(q.z) * sSc[cb + 4] + sSh[cb + 4];
    o1.y = bhi(q.z) * sSc[cb + 5] + sSh[cb + 5];
    o1.z = blo(q.w) * sSc[cb + 6] + sSh[cb + 6];
    o1.w = bhi(q.w) * sSc[cb + 7] + sSh[cb + 7];
    out4[2 * i] = o0;
    out4[2 * i + 1] = o1;
  }
}

// ======================= Fallback kernels =======================
__global__ __launch_bounds__(256) void hist_kernel(const int* __restrict__ ei,
                                                   int* __restrict__ deg,
                                                   int E_) {
  int stride = gridDim.x * blockDim.x;
  for (int e = blockIdx.x * blockDim.x + threadIdx.x; e < E_; e += stride)
    atomicAdd(&deg[ei[E_ + e]], 1);
}

__global__ __launch_bounds__(256) void scan_block_kernel(
    const int* __restrict__ deg, int* __restrict__ offs,
    int* __restrict__ partials, int n) {
  const int tid = threadIdx.x;
  int g = blockIdx.x * 1024 + tid * 4;
  int v0 = (g + 0 < n) ? deg[g + 0] : 0;
  int v1 = (g + 1 < n) ? deg[g + 1] : 0;
  int v2 = (g + 2 < n) ? deg[g + 2] : 0;
  int v3 = (g + 3 < n) ? deg[g + 3] : 0;
  int tsum = v0 + v1 + v2 + v3;
  __shared__ int s[256];
  s[tid] = tsum;
  __syncthreads();
  for (int off = 1; off < 256; off <<= 1) {
    int t = (tid >= off) ? s[tid - off] : 0;
    __syncthreads();
    s[tid] += t;
    __syncthreads();
  }
  int excl = s[tid] - tsum;
  if (g + 0 < n) offs[g + 0] = excl;
  if (g + 1 < n) offs[g + 1] = excl + v0;
  if (g + 2 < n) offs[g + 2] = excl + v0 + v1;
  if (g + 3 < n) offs[g + 3] = excl + v0 + v1 + v2;
  if (tid == 255) partials[blockIdx.x] = s[255];
}

__global__ void scan_partials_kernel(int* __restrict__ partials, int nb) {
  const int tid = threadIdx.x;
  int v = (tid < nb) ? partials[tid] : 0;
  __shared__ int s[128];
  s[tid] = v;
  __syncthreads();
  for (int off = 1; off < 128; off <<= 1) {
    int t = (tid >= off) ? s[tid - off] : 0;
    __syncthreads();
    s[tid] += t;
    __syncthreads();
  }
  if (tid < nb) partials[tid] = s[tid] - v;
}

__global__ __launch_bounds__(256) void scan_add_kernel(
    int* __restrict__ offs, int* __restrict__ cursor,
    const int* __restrict__ partials, int n, int E_) {
  int g = blockIdx.x * blockDim.x + threadIdx.x;
  if (g < n) {
    int v = offs[g] + partials[g >> 10];
    offs[g] = v;
    cursor[g] = v;
  }
  if (g == 0) offs[n] = E_;
}

__global__ __launch_bounds__(256) void fill_kernel(const int* __restrict__ ei,
                                                   int* __restrict__ cursor,
                                                   int* __restrict__ csr,
                                                   int E_) {
  const int G = gridDim.x * blockDim.x;
  int g = blockIdx.x * blockDim.x + threadIdx.x;
  for (long long base = g; base < E_; base += (long long)G * 8) {
    int src[8], dst[8], pos[8];
#pragma unroll
    for (int k = 0; k < 8; ++k) {
      long long e = base + (long long)k * G;
      src[k] = (e < E_) ? ei[e] : -1;
      dst[k] = (e < E_) ? ei[E_ + e] : 0;
    }
#pragma unroll
    for (int k = 0; k < 8; ++k)
      if (src[k] >= 0) pos[k] = atomicAdd(&cursor[dst[k]], 1);
#pragma unroll
    for (int k = 0; k < 8; ++k)
      if (src[k] >= 0) csr[pos[k]] = src[k];
  }
}

__global__ __launch_bounds__(128) void gather_f32_kernel(
    const float* __restrict__ x, const int* __restrict__ offs,
    const int* __restrict__ csr, float* __restrict__ h) {
  int n = blockIdx.x;
  int c = threadIdx.x;
  int beg = offs[n], end = offs[n + 1];
  float acc = x[(size_t)n * DIM + c];
  for (int j = beg; j < end; ++j) acc += x[(size_t)csr[j] * DIM + c];
  h[(size_t)n * DIM + c] = acc;
}

__global__ __launch_bounds__(256) void scatter_kernel(
    const float* __restrict__ x, const int* __restrict__ ei,
    float* __restrict__ h, int E_) {
  long long total = (long long)E_ * 32;
  long long stride = (long long)gridDim.x * blockDim.x;
  for (long long idx = (long long)blockIdx.x * blockDim.x + threadIdx.x;
       idx < total; idx += stride) {
    int e = (int)(idx >> 5);
    int q = (int)(idx & 31);
    float4 v =
        *reinterpret_cast<const float4*>(x + (size_t)ei[e] * DIM + q * 4);
    float* p = h + (size_t)ei[E_ + e] * DIM + q * 4;
    atomicAdd(p + 0, v.x);
    atomicAdd(p + 1, v.y);
    atomicAdd(p + 2, v.z);
    atomicAdd(p + 3, v.w);
  }
}

__global__ __launch_bounds__(256) void add_x_kernel(const float* __restrict__ x,
                                                    float* __restrict__ h) {
  size_t total = (size_t)N_NODES * DIM / 4;
  size_t stride = (size_t)gridDim.x * blockDim.x;
  for (size_t i = (size_t)blockIdx.x * blockDim.x + threadIdx.x; i < total;
       i += stride) {
    float4 v = reinterpret_cast<float4*>(h)[i];
    float4 xv = reinterpret_cast<const float4*>(x)[i];
    v.x += xv.x; v.y += xv.y; v.z += xv.z; v.w += xv.w;
    reinterpret_cast<float4*>(h)[i] = v;
  }
}

__global__ __launch_bounds__(256) void mlp_valu_kernel(
    float* hbuf, const float* __restrict__ W1, const float* __restrict__ b1,
    const float* __restrict__ W2, const float* __restrict__ b2) {
  __shared__ float sW[DIM * DIM];
  __shared__ float sH[32][DIM];
  const int tid = threadIdx.x;
  const int col = tid & 127;
  const int rhalf = tid >> 7;
  const int row0 = blockIdx.x * 32;

  for (int i = tid; i < DIM * DIM; i += 256) sW[i] = W1[i];
  for (int i = tid; i < 32 * DIM; i += 256) {
    int r = i >> 7, c = i & 127;
    sH[r][c] = hbuf[(size_t)(row0 + r) * DIM + c];
  }
  __syncthreads();
  float acc[16];
  float bias = b1[col];
#pragma unroll
  for (int j = 0; j < 16; ++j) acc[j] = bias;
#pragma unroll 4
  for (int k = 0; k < DIM; ++k) {
    float w = sW[k * DIM + col];
#pragma unroll
    for (int j = 0; j < 16; ++j) acc[j] = fmaf(sH[2 * j + rhalf][k], w, acc[j]);
  }
  __syncthreads();
  for (int i = tid; i < DIM * DIM; i += 256) sW[i] = W2[i];
#pragma unroll
  for (int j = 0; j < 16; ++j) sH[2 * j + rhalf][col] = fmaxf(acc[j], 0.f);
  __syncthreads();
  float bias2 = b2[col];
#pragma unroll
  for (int j = 0; j < 16; ++j) acc[j] = bias2;
#pragma unroll 4
  for (int k = 0; k < DIM; ++k) {
    float w = sW[k * DIM + col];
#pragma unroll
    for (int j = 0; j < 16; ++j) acc[j] = fmaf(sH[2 * j + rhalf][k], w, acc[j]);
  }
#pragma unroll
  for (int j = 0; j < 16; ++j)
    hbuf[(size_t)(row0 + 2 * j + rhalf) * DIM + col] = fmaxf(acc[j], 0.f);
}

__global__ __launch_bounds__(256) void bn_stats_kernel(
    const float* __restrict__ h, float* __restrict__ stats) {
  int col = threadIdx.x & 127;
  int rsub = threadIdx.x >> 7;
  int rstep = gridDim.x * 2;
  float s = 0.f, ss = 0.f;
  for (int r = blockIdx.x * 2 + rsub; r < N_NODES; r += rstep) {
    float v = h[(size_t)r * DIM + col];
    s += v;
    ss += v * v;
  }
  __shared__ float ls[256], lss[256];
  ls[threadIdx.x] = s;
  lss[threadIdx.x] = ss;
  __syncthreads();
  if (threadIdx.x < 128) {
    atomicAdd(&stats[col], ls[threadIdx.x] + ls[threadIdx.x + 128]);
    atomicAdd(&stats[DIM + col], lss[threadIdx.x] + lss[threadIdx.x + 128]);
  }
}

__global__ void bn_scale_kernel(const float* __restrict__ stats,
                                const float* __restrict__ gamma,
                                const float* __restrict__ beta,
                                float* __restrict__ sc) {
  int c = threadIdx.x;  // 128
  float mean = stats[c] / (float)N_NODES;
  float var = stats[DIM + c] / (float)N_NODES - mean * mean;
  float scale = gamma[c] * rsqrtf(var + 1e-5f);
  sc[c] = scale;
  sc[DIM + c] = beta[c] - mean * scale;
}

__global__ __launch_bounds__(256) void bn_apply_kernel(
    float* __restrict__ h, const float* __restrict__ sc) {
  size_t total = (size_t)N_NODES * DIM / 4;
  size_t stride = (size_t)gridDim.x * blockDim.x;
  for (size_t i = (size_t)blockIdx.x * blockDim.x + threadIdx.x; i < total;
       i += stride) {
    float4 v = reinterpret_cast<float4*>(h)[i];
    int c = (int)((i * 4) & 127);
    v.x = v.x * sc[c + 0] + sc[DIM + c + 0];
    v.y = v.y * sc[c + 1] + sc[DIM + c + 1];
    v.z = v.z * sc[c + 2] + sc[DIM + c + 2];
    v.w = v.w * sc[c + 3] + sc[DIM + c + 3];
    reinterpret_cast<float4*>(h)[i] = v;
  }
}

extern "C" void kernel_launch(void* const* d_in, const int* in_sizes, int n_in,
                              void* d_out, int out_size, void* d_ws,
                              size_t ws_size, hipStream_t stream) {
  const float* x = (const float*)d_in[0];
  const int* ei = (const int*)d_in[1];
  const float* W1 = (const float*)d_in[3];
  const float* b1 = (const float*)d_in[4];
  const float* W2 = (const float*)d_in[5];
  const float* b2 = (const float*)d_in[6];
  const float* gamma = (const float*)d_in[7];
  const float* beta = (const float*)d_in[8];
  float* out = (float*)d_out;
  int E_ = in_sizes[1] / 2;

  // ---- full-path workspace layout (16B-aligned fields) ----
  const size_t XB_B = (size_t)N_NODES * DIM * 2;  // 25.6e6
  char* w = (char*)d_ws;
  size_t off = 0;
  u16* xb = (u16*)(w + off); off += XB_B;
  u16* hb = (u16*)(w + off); off += XB_B;
  u16* Wt1 = (u16*)(w + off); off += 32768;
  u16* Wt2 = (u16*)(w + off); off += 32768;
  u32* packed = (u32*)(w + off); off += (size_t)E_ * 4;
  int* bcnt = (int*)(w + off); off += 1600;
  float* stats = (float*)(w + off); off += 3072;
  int* boffs = (int*)(w + off); off += 1600;
  int* gcur = (int*)(w + off); off += 1600;
  size_t need_full = off;
  float* pstats = (float*)xb;  // xb is dead after sortgather

  // ---- CSR-only fallback layout ----
  int* f_offs = (int*)d_ws;
  int* f_cursor = f_offs + N_NODES + 1;
  int* f_partials = f_cursor + N_NODES;
  int* f_csr = f_partials + 128;
  float* f_stats = (float*)(f_csr + E_);
  size_t need_csr = ((size_t)2 * N_NODES + 129 + E_) * 4 + 3072;

  const int nScanBlocks = (N_NODES + 1023) / 1024;  // 98
  const int nEdgeBlocks = (E_ + 2047) / 2048;
  const int nPartBlocks = (E_ + PT_TILE - 1) / PT_TILE;
  const int nMlpBlocks = (N_NODES + 63) / 64;  // 1563

  if (ws_size >= need_full) {
    hipMemsetAsync(bcnt, 0, 1600 + 3072, stream);  // bcnt + stats
    prep_kernel<<<640, 256, 0, stream>>>(W1, Wt1, W2, Wt2, ei, bcnt, E_);
    bscan_kernel<<<1, 256, 0, stream>>>(bcnt, boffs, gcur);
    part_cvt_kernel<<<nPartBlocks + 1024, PT_THR, 0, stream>>>(
        ei, gcur, packed, E_, x, xb);
    sortgather_kernel<<<NBUCK, 1024, 0, stream>>>(
        packed, boffs, (const uint4*)xb, (uint4*)hb);
    mlp_mfma_kernel<<<nMlpBlocks, 256, 0, stream>>>(hb, Wt1, Wt2, b1, b2,
                                                    pstats);
    bn_reduce_kernel<<<32, 256, 0, stream>>>(pstats, stats, nMlpBlocks);
    bn_apply_bf16_kernel<<<2048, 256, 0, stream>>>(
        (const uint4*)hb, stats, gamma, beta, (float4*)out);
  } else if (ws_size >= need_csr) {
    hipMemsetAsync(f_cursor, 0, (size_t)N_NODES * sizeof(int), stream);
    hipMemsetAsync(f_stats, 0, 768 * sizeof(float), stream);
    hist_kernel<<<2048, 256, 0, stream>>>(ei, f_cursor, E_);
    scan_block_kernel<<<nScanBlocks, 256, 0, stream>>>(f_cursor, f_offs,
                                                       f_partials, N_NODES);
    scan_partials_kernel<<<1, 128, 0, stream>>>(f_partials, nScanBlocks);
    scan_add_kernel<<<(N_NODES + 255) / 256, 256, 0, stream>>>(
        f_offs, f_cursor, f_partials, N_NODES, E_);
    fill_kernel<<<nEdgeBlocks, 256, 0, stream>>>(ei, f_cursor, f_csr, E_);
    gather_f32_kernel<<<N_NODES, 128, 0, stream>>>(x, f_offs, f_csr, out);
    mlp_valu_kernel<<<(N_NODES + 31) / 32, 256, 0, stream>>>(out, W1, b1, W2,
                                                             b2);
    bn_stats_kernel<<<1024, 256, 0, stream>>>(out, f_stats);
    bn_scale_kernel<<<1, 128, 0, stream>>>(f_stats, gamma, beta, f_stats + 256);
    bn_apply_kernel<<<2048, 256, 0, stream>>>(out, f_stats + 256);
  } else {
    float* s2 = (float*)d_ws;
    hipMemsetAsync(out, 0, (size_t)N_NODES * DIM * sizeof(float), stream);
    hipMemsetAsync(s2, 0, 768 * sizeof(float), stream);
    scatter_kernel<<<4096, 256, 0, stream>>>(x, ei, out, E_);
    add_x_kernel<<<2048, 256, 0, stream>>>(x, out);
    mlp_valu_kernel<<<(N_NODES + 31) / 32, 256, 0, stream>>>(out, W1, b1, W2,
                                                             b2);
    bn_stats_kernel<<<1024, 256, 0, stream>>>(out, s2);
    bn_scale_kernel<<<1, 128, 0, stream>>>(s2, gamma, beta, s2 + 256);
    bn_apply_kernel<<<2048, 256, 0, stream>>>(out, s2 + 256);
  }
}

// Round 13
// 259.175 us; speedup vs baseline: 1.1163x; 1.0013x over previous
//
#include <hip/hip_runtime.h>

#define N_NODES 100000
#define DIM 128
#define PT_TILE 8192  // edges per partition block
#define PT_THR 512

// Tier1: fixed-stride buckets, 128 nodes each
#define NB1 782      // ceil(N/128)
#define CAP1 4864    // per-bucket stride (mean 4092, +12 sigma)
// Tier2 (R12 path): 256-node buckets, exact offsets via bhist/bscan
#define NB2 391
#define CAP2 12288

typedef unsigned int u32;
typedef unsigned short u16;
typedef __attribute__((ext_vector_type(8))) short bf16x8;
typedef __attribute__((ext_vector_type(4))) float f32x4;

__device__ __forceinline__ float bf16_to_f(u16 v) {
  return __uint_as_float(((u32)v) << 16);
}
__device__ __forceinline__ u16 f_to_bf16(float f) {
  u32 b = __float_as_uint(f);
  b += 0x7fff + ((b >> 16) & 1);  // round-to-nearest-even
  return (u16)(b >> 16);
}
__device__ __forceinline__ float blo(u32 q) { return __uint_as_float(q << 16); }
__device__ __forceinline__ float bhi(u32 q) {
  return __uint_as_float(q & 0xffff0000u);
}
__device__ __forceinline__ u32 packbf(float lo, float hi) {
  return ((u32)f_to_bf16(hi) << 16) | (u32)f_to_bf16(lo);
}

// ====== Tier1 prep: cvt_W1 + cvt_W2 + gcur-init + stats-zero ======
__global__ __launch_bounds__(256) void prep1_kernel(
    const float* __restrict__ W1, u16* __restrict__ Wt1,
    const float* __restrict__ W2, u16* __restrict__ Wt2,
    int* __restrict__ gcur, float* __restrict__ stats) {
  int blk = blockIdx.x;
  if (blk < 64) {
    int id = blk * 256 + threadIdx.x;  // id = c*128 + k
    Wt1[id] = f_to_bf16(W1[(id & 127) * DIM + (id >> 7)]);
  } else if (blk < 128) {
    int id = (blk - 64) * 256 + threadIdx.x;
    Wt2[id] = f_to_bf16(W2[(id & 127) * DIM + (id >> 7)]);
  } else if (blk == 128) {
    for (int i = threadIdx.x; i < NB1; i += 256) gcur[i] = i * CAP1;
  } else {
    for (int i = threadIdx.x; i < 768; i += 256) stats[i] = 0.f;
  }
}

// ====== Tier2 prep: cvt_W + bhist (R12) ======
__global__ __launch_bounds__(256) void prep2_kernel(
    const float* __restrict__ W1, u16* __restrict__ Wt1,
    const float* __restrict__ W2, u16* __restrict__ Wt2,
    const int* __restrict__ ei, int* __restrict__ bcnt, int E_) {
  int blk = blockIdx.x;
  if (blk < 64) {
    int id = blk * 256 + threadIdx.x;
    Wt1[id] = f_to_bf16(W1[(id & 127) * DIM + (id >> 7)]);
  } else if (blk < 128) {
    int id = (blk - 64) * 256 + threadIdx.x;
    Wt2[id] = f_to_bf16(W2[(id & 127) * DIM + (id >> 7)]);
  } else {
    __shared__ int lc[NB2];
    for (int i = threadIdx.x; i < NB2; i += 256) lc[i] = 0;
    __syncthreads();
    const int* dst = ei + E_;
    int G = 512 * 256;
    int g = (blk - 128) * 256 + threadIdx.x;
    int n4 = E_ >> 2;
    const int4* d4 = (const int4*)dst;
    for (int i = g; i < n4; i += G) {
      int4 v = d4[i];
      atomicAdd(&lc[((u32)v.x) >> 8], 1);
      atomicAdd(&lc[((u32)v.y) >> 8], 1);
      atomicAdd(&lc[((u32)v.z) >> 8], 1);
      atomicAdd(&lc[((u32)v.w) >> 8], 1);
    }
    for (int e = (n4 << 2) + g; e < E_; e += G)
      atomicAdd(&lc[((u32)dst[e]) >> 8], 1);
    __syncthreads();
    for (int i = threadIdx.x; i < NB2; i += 256)
      if (lc[i]) atomicAdd(&bcnt[i], lc[i]);
  }
}

__global__ void bscan_kernel(const int* __restrict__ bcnt,
                             int* __restrict__ boffs, int* __restrict__ gcur) {
  __shared__ int s[256];
  int t = threadIdx.x;
  int v0 = (2 * t < NB2) ? bcnt[2 * t] : 0;
  int v1 = (2 * t + 1 < NB2) ? bcnt[2 * t + 1] : 0;
  int ts = v0 + v1;
  s[t] = ts;
  __syncthreads();
  for (int o = 1; o < 256; o <<= 1) {
    int u = (t >= o) ? s[t - o] : 0;
    __syncthreads();
    s[t] += u;
    __syncthreads();
  }
  int excl = s[t] - ts;
  if (2 * t <= NB2) boffs[2 * t] = excl;
  if (2 * t + 1 <= NB2) boffs[2 * t + 1] = excl + v0;
  if (2 * t < NB2) gcur[2 * t] = excl;
  if (2 * t + 1 < NB2) gcur[2 * t + 1] = excl + v0;
}

// ========= partition (+ concurrent cvt_x), templated on bucket shape =====
// SHIFT: dst>>SHIFT = bucket; NB: bucket count. gcur holds running cursors
// (tier1: pre-set to b*CAP1; tier2: exclusive offsets from bscan).
template <int SHIFT, int NB>
__global__ __launch_bounds__(PT_THR) void part_cvt_kernel(
    const int* __restrict__ ei, int* __restrict__ gcur,
    u32* __restrict__ packed, int E_, const float* __restrict__ x,
    u16* __restrict__ xb) {
  __shared__ u32 keys[PT_TILE];   // 32 KB
  __shared__ u16 bid[PT_TILE];    // 16 KB
  __shared__ int lh[NB];
  __shared__ int lpos[NB];
  __shared__ int gpos[NB];
  __shared__ int ss[PT_THR];
  const int nPart = (E_ + PT_TILE - 1) / PT_TILE;
  const int t = threadIdx.x;
  constexpr u32 LOWMASK = (1u << SHIFT) - 1u;

  if (blockIdx.x >= nPart) {
    int cb = blockIdx.x - nPart;  // 0..1023
    int total = N_NODES * DIM / 4;
    int stride = 1024 * PT_THR;
    for (int i = cb * PT_THR + t; i < total; i += stride) {
      float4 v = reinterpret_cast<const float4*>(x)[i];
      ushort4 o;
      o.x = f_to_bf16(v.x);
      o.y = f_to_bf16(v.y);
      o.z = f_to_bf16(v.z);
      o.w = f_to_bf16(v.w);
      reinterpret_cast<ushort4*>(xb)[i] = o;
    }
    return;
  }

  const int base = blockIdx.x * PT_TILE;
  const int cnt = min(PT_TILE, E_ - base);

  for (int i = t; i < NB; i += PT_THR) lh[i] = 0;
  __syncthreads();

  u32 pk[16];
  int bb[16];
#pragma unroll
  for (int k = 0; k < 16; ++k) {
    int e = base + k * PT_THR + t;
    if (k * PT_THR + t < cnt) {
      int src = ei[e];
      u32 dst = (u32)ei[E_ + e];
      bb[k] = (int)(dst >> SHIFT);
      pk[k] = (u32)src | ((dst & LOWMASK) << 17);
      atomicAdd(&lh[bb[k]], 1);
    } else {
      bb[k] = -1;
    }
  }
  __syncthreads();

  // block scan over NB buckets, EPT buckets per thread
  constexpr int EPT = (NB + PT_THR - 1) / PT_THR;
  int myv[EPT];
  int tsum = 0;
#pragma unroll
  for (int e2 = 0; e2 < EPT; ++e2) {
    int b2 = t * EPT + e2;
    myv[e2] = (b2 < NB) ? lh[b2] : 0;
    tsum += myv[e2];
  }
  ss[t] = tsum;
  __syncthreads();
  for (int o = 1; o < PT_THR; o <<= 1) {
    int u = (t >= o) ? ss[t - o] : 0;
    __syncthreads();
    ss[t] += u;
    __syncthreads();
  }
  {
    int excl = ss[t] - tsum;
#pragma unroll
    for (int e2 = 0; e2 < EPT; ++e2) {
      int b2 = t * EPT + e2;
      if (b2 < NB) {
        lpos[b2] = excl;
        if (myv[e2] > 0) gpos[b2] = atomicAdd(&gcur[b2], myv[e2]);
        excl += myv[e2];
      }
    }
  }
  __syncthreads();

#pragma unroll
  for (int k = 0; k < 16; ++k) {
    if (bb[k] >= 0) {
      int p = atomicAdd(&lpos[bb[k]], 1);
      keys[p] = pk[k];
      bid[p] = (u16)bb[k];
    }
  }
  __syncthreads();

  for (int i = t; i < cnt; i += PT_THR) {
    int b = bid[i];
    int startb = lpos[b] - lh[b];
    packed[gpos[b] + (i - startb)] = keys[i];
  }
}

// ===== Fused bucket-sort + gather, templated =====
// FIXED=true: bucket b at packed[b*LCAP], count = gcur[b]-b*LCAP.
// FIXED=false: offsets from boffs. HN = nodes/bucket = 1<<SHIFT.
template <int SHIFT, int THR, int LCAP, bool FIXED>
__global__ __launch_bounds__(THR) void sortgather_kernel(
    const u32* __restrict__ packed, const int* __restrict__ boffs,
    const int* __restrict__ gcur, const uint4* __restrict__ xb4,
    uint4* __restrict__ hb4) {
  constexpr int HN = 1 << SHIFT;
  constexpr int WAVES = THR / 64;
  constexpr int K = HN / WAVES;
  __shared__ u32 sorted_[LCAP];
  __shared__ int hist[HN], cur[HN], ssc[HN];
  __shared__ int nodeoff[HN + 1];
  const int b = blockIdx.x;
  const int t = threadIdx.x;
  int base, cnt;
  if (FIXED) {
    base = b * LCAP;
    cnt = gcur[b] - base;
  } else {
    base = boffs[b];
    cnt = boffs[b + 1] - base;
  }
  if (cnt > LCAP) cnt = LCAP;
  if (cnt < 0) cnt = 0;

  if (t < HN) hist[t] = 0;
  __syncthreads();
  for (int i = t; i < cnt; i += THR)
    atomicAdd(&hist[packed[base + i] >> 17], 1);
  __syncthreads();
  if (t < HN) ssc[t] = hist[t];
  __syncthreads();
  for (int o = 1; o < HN; o <<= 1) {
    int u = 0;
    if (t < HN && t >= o) u = ssc[t - o];
    __syncthreads();
    if (t < HN) ssc[t] += u;
    __syncthreads();
  }
  if (t < HN) {
    int excl = ssc[t] - hist[t];
    cur[t] = excl;
    nodeoff[t] = excl;
  }
  if (t == 0) nodeoff[HN] = cnt;
  __syncthreads();
  for (int i = t; i < cnt; i += THR) {
    u32 v = packed[base + i];
    int p = atomicAdd(&cur[v >> 17], 1);
    sorted_[p] = v & 0x1FFFFu;
  }
  __syncthreads();

  // ---- gather phase ----
  const int wv = t >> 6;
  const int lane = t & 63;
  const int g = lane >> 4;
  const int l = lane & 15;
#pragma unroll 1
  for (int k = 0; k < K; ++k) {
    int nl = wv + k * WAVES;
    int n = b * HN + nl;
    if (n >= N_NODES) break;
    int beg = nodeoff[nl], end = nodeoff[nl + 1];
    float a0 = 0.f, a1 = 0.f, a2 = 0.f, a3 = 0.f;
    float a4 = 0.f, a5 = 0.f, a6 = 0.f, a7 = 0.f;
    if (g == 0) {  // self row
      uint4 q = xb4[(size_t)n * 16 + l];
      a0 = blo(q.x); a1 = bhi(q.x);
      a2 = blo(q.y); a3 = bhi(q.y);
      a4 = blo(q.z); a5 = bhi(q.z);
      a6 = blo(q.w); a7 = bhi(q.w);
    }
    int j = beg + g;
    for (; j + 12 < end; j += 16) {
      int s0 = sorted_[j], s1 = sorted_[j + 4];
      int s2 = sorted_[j + 8], s3 = sorted_[j + 12];
      uint4 q0 = xb4[(size_t)s0 * 16 + l];
      uint4 q1 = xb4[(size_t)s1 * 16 + l];
      uint4 q2 = xb4[(size_t)s2 * 16 + l];
      uint4 q3 = xb4[(size_t)s3 * 16 + l];
      a0 += blo(q0.x); a1 += bhi(q0.x);
      a2 += blo(q0.y); a3 += bhi(q0.y);
      a4 += blo(q0.z); a5 += bhi(q0.z);
      a6 += blo(q0.w); a7 += bhi(q0.w);
      a0 += blo(q1.x); a1 += bhi(q1.x);
      a2 += blo(q1.y); a3 += bhi(q1.y);
      a4 += blo(q1.z); a5 += bhi(q1.z);
      a6 += blo(q1.w); a7 += bhi(q1.w);
      a0 += blo(q2.x); a1 += bhi(q2.x);
      a2 += blo(q2.y); a3 += bhi(q2.y);
      a4 += blo(q2.z); a5 += bhi(q2.z);
      a6 += blo(q2.w); a7 += bhi(q2.w);
      a0 += blo(q3.x); a1 += bhi(q3.x);
      a2 += blo(q3.y); a3 += bhi(q3.y);
      a4 += blo(q3.z); a5 += bhi(q3.z);
      a6 += blo(q3.w); a7 += bhi(q3.w);
    }
    for (; j < end; j += 4) {
      uint4 q = xb4[(size_t)sorted_[j] * 16 + l];
      a0 += blo(q.x); a1 += bhi(q.x);
      a2 += blo(q.y); a3 += bhi(q.y);
      a4 += blo(q.z); a5 += bhi(q.z);
      a6 += blo(q.w); a7 += bhi(q.w);
    }
    a0 += __shfl_xor(a0, 16); a1 += __shfl_xor(a1, 16);
    a2 += __shfl_xor(a2, 16); a3 += __shfl_xor(a3, 16);
    a4 += __shfl_xor(a4, 16); a5 += __shfl_xor(a5, 16);
    a6 += __shfl_xor(a6, 16); a7 += __shfl_xor(a7, 16);
    a0 += __shfl_xor(a0, 32); a1 += __shfl_xor(a1, 32);
    a2 += __shfl_xor(a2, 32); a3 += __shfl_xor(a3, 32);
    a4 += __shfl_xor(a4, 32); a5 += __shfl_xor(a5, 32);
    a6 += __shfl_xor(a6, 32); a7 += __shfl_xor(a7, 32);
    if (g == 0) {
      uint4 o;
      o.x = packbf(a0, a1);
      o.y = packbf(a2, a3);
      o.z = packbf(a4, a5);
      o.w = packbf(a6, a7);
      hb4[(size_t)n * 16 + l] = o;
    }
  }
}

// ===== MFMA MLP: bf16 h2 in place in hb + streaming per-block partials ====
__global__ __launch_bounds__(256) void mlp_mfma_kernel(
    u16* __restrict__ hb, const u16* __restrict__ Wt1,
    const u16* __restrict__ Wt2, const float* __restrict__ b1,
    const float* __restrict__ b2, float* __restrict__ pstats) {
  __shared__ u16 sH1[4][16 * DIM];  // 16 KB
  __shared__ float sS[4][128], sQ[4][128];  // 4 KB
  const int tid = threadIdx.x;
  const int wv = tid >> 6;
  const int lane = tid & 63;
  const int lr = lane & 15;
  const int lq = lane >> 4;
  const int row0 = blockIdx.x * 64 + wv * 16;

  // ---- layer 1 ----
  bf16x8 a[4];
  {
    int r = row0 + lr;
    if (r > N_NODES - 1) r = N_NODES - 1;
#pragma unroll
    for (int ks = 0; ks < 4; ++ks)
      a[ks] = *reinterpret_cast<const bf16x8*>(hb + (size_t)r * DIM + ks * 32 +
                                               lq * 8);
  }
  f32x4 acc[8];
#pragma unroll
  for (int ct = 0; ct < 8; ++ct) {
    f32x4 c = {0.f, 0.f, 0.f, 0.f};
#pragma unroll
    for (int ks = 0; ks < 4; ++ks) {
      bf16x8 b = *reinterpret_cast<const bf16x8*>(
          Wt1 + (ct * 16 + lr) * DIM + ks * 32 + lq * 8);
      c = __builtin_amdgcn_mfma_f32_16x16x32_bf16(a[ks], b, c, 0, 0, 0);
    }
    acc[ct] = c;
  }
  char* slab = reinterpret_cast<char*>(&sH1[wv][0]);
#pragma unroll
  for (int ct = 0; ct < 8; ++ct) {
    int c = ct * 16 + lr;
    float bias = b1[c];
#pragma unroll
    for (int j = 0; j < 4; ++j) {
      int rl = lq * 4 + j;
      float y = fmaxf(acc[ct][j] + bias, 0.f);
      int byte = rl * 256 + ((c * 2) ^ ((rl & 7) << 4));
      *reinterpret_cast<u16*>(slab + byte) = f_to_bf16(y);
    }
  }
  __syncthreads();

  // ---- layer 2 ----
  bf16x8 a2[4];
#pragma unroll
  for (int ks = 0; ks < 4; ++ks) {
    int byte = lr * 256 + (((ks * 32 + lq * 8) * 2) ^ ((lr & 7) << 4));
    a2[ks] = *reinterpret_cast<const bf16x8*>(slab + byte);
  }
#pragma unroll
  for (int ct = 0; ct < 8; ++ct) {
    f32x4 c = {0.f, 0.f, 0.f, 0.f};
#pragma unroll
    for (int ks = 0; ks < 4; ++ks) {
      bf16x8 b = *reinterpret_cast<const bf16x8*>(
          Wt2 + (ct * 16 + lr) * DIM + ks * 32 + lq * 8);
      c = __builtin_amdgcn_mfma_f32_16x16x32_bf16(a2[ks], b, c, 0, 0, 0);
    }
    acc[ct] = c;
  }
  // ---- epilogue: bf16 h2 back into hb + per-column (s, ss) of quantized ----
  float ls[8], lss[8];
#pragma unroll
  for (int ct = 0; ct < 8; ++ct) {
    int c = ct * 16 + lr;
    float bias = b2[c];
    ls[ct] = 0.f;
    lss[ct] = 0.f;
#pragma unroll
    for (int j = 0; j < 4; ++j) {
      int r = row0 + lq * 4 + j;
      float y = fmaxf(acc[ct][j] + bias, 0.f);
      u16 yq = f_to_bf16(y);
      float yf = bf16_to_f(yq);
      if (r < N_NODES) {
        hb[(size_t)r * DIM + c] = yq;
        ls[ct] += yf;
        lss[ct] += yf * yf;
      }
    }
  }
#pragma unroll
  for (int ct = 0; ct < 8; ++ct) {
    float s = ls[ct], q = lss[ct];
    s += __shfl_xor(s, 16);
    q += __shfl_xor(q, 16);
    s += __shfl_xor(s, 32);
    q += __shfl_xor(q, 32);
    if (lq == 0) {
      sS[wv][ct * 16 + lr] = s;
      sQ[wv][ct * 16 + lr] = q;
    }
  }
  __syncthreads();
  {
    int t = tid;
    float v;
    if (t < 128)
      v = sS[0][t] + sS[1][t] + sS[2][t] + sS[3][t];
    else
      v = sQ[0][t - 128] + sQ[1][t - 128] + sQ[2][t - 128] + sQ[3][t - 128];
    pstats[(size_t)blockIdx.x * 256 + t] = v;  // streaming, no contention
  }
}

// ======================= BatchNorm =======================
__global__ __launch_bounds__(256) void bn_reduce_kernel(
    const float* __restrict__ pstats, float* __restrict__ stats, int nblk) {
  int t = threadIdx.x;
  float v = 0.f;
  for (int i = blockIdx.x; i < nblk; i += gridDim.x)
    v += pstats[(size_t)i * 256 + t];
  atomicAdd(&stats[t], v);
}

__global__ __launch_bounds__(256) void bn_apply_bf16_kernel(
    const uint4* __restrict__ hb4, const float* __restrict__ stats,
    const float* __restrict__ gamma, const float* __restrict__ beta,
    float4* __restrict__ out4) {
  __shared__ float sSc[128], sSh[128];
  int t = threadIdx.x;
  if (t < 128) {
    float mean = stats[t] / (float)N_NODES;
    float var = stats[128 + t] / (float)N_NODES - mean * mean;
    float scale = gamma[t] * rsqrtf(var + 1e-5f);
    sSc[t] = scale;
    sSh[t] = beta[t] - mean * scale;
  }
  __syncthreads();
  int total = N_NODES * 16;  // uint4 per row of 128 bf16
  int stride = gridDim.x * 256;
  for (int i = blockIdx.x * 256 + t; i < total; i += stride) {
    uint4 q = hb4[i];
    int cb = (i & 15) * 8;
    float4 o0, o1;
    o0.x = blo(q.x) * sSc[cb + 0] + sSh[cb + 0];
    o0.y = bhi(q.x) * sSc[cb + 1] + sSh[cb + 1];
    o0.z = blo(q.y) * sSc[cb + 2] + sSh[cb + 2];
    o0.w = bhi(q.y) * sSc[cb + 3] + sSh[cb + 3];
    o1.x = blo(q.z) * sSc[cb + 4] + sSh[cb + 4];
    o1.y = bhi(q.z) * sSc[cb + 5] + sSh[cb + 5];
    o1.z = blo(q.w) * sSc[cb + 6] + sSh[cb + 6];
    o1.w = bhi(q.w) * sSc[cb + 7] + sSh[cb + 7];
    out4[2 * i] = o0;
    out4[2 * i + 1] = o1;
  }
}

// ======================= Minimal atomic fallback =======================
__global__ __launch_bounds__(256) void scatter_kernel(
    const float* __restrict__ x, const int* __restrict__ ei,
    float* __restrict__ h, int E_) {
  long long total = (long long)E_ * 32;
  long long stride = (long long)gridDim.x * blockDim.x;
  for (long long idx = (long long)blockIdx.x * blockDim.x + threadIdx.x;
       idx < total; idx += stride) {
    int e = (int)(idx >> 5);
    int q = (int)(idx & 31);
    float4 v =
        *reinterpret_cast<const float4*>(x + (size_t)ei[e] * DIM + q * 4);
    float* p = h + (size_t)ei[E_ + e] * DIM + q * 4;
    atomicAdd(p + 0, v.x);
    atomicAdd(p + 1, v.y);
    atomicAdd(p + 2, v.z);
    atomicAdd(p + 3, v.w);
  }
}

__global__ __launch_bounds__(256) void add_x_kernel(const float* __restrict__ x,
                                                    float* __restrict__ h) {
  size_t total = (size_t)N_NODES * DIM / 4;
  size_t stride = (size_t)gridDim.x * blockDim.x;
  for (size_t i = (size_t)blockIdx.x * blockDim.x + threadIdx.x; i < total;
       i += stride) {
    float4 v = reinterpret_cast<float4*>(h)[i];
    float4 xv = reinterpret_cast<const float4*>(x)[i];
    v.x += xv.x; v.y += xv.y; v.z += xv.z; v.w += xv.w;
    reinterpret_cast<float4*>(h)[i] = v;
  }
}

__global__ __launch_bounds__(256) void mlp_valu_kernel(
    float* hbuf, const float* __restrict__ W1, const float* __restrict__ b1,
    const float* __restrict__ W2, const float* __restrict__ b2) {
  __shared__ float sW[DIM * DIM];
  __shared__ float sH[32][DIM];
  const int tid = threadIdx.x;
  const int col = tid & 127;
  const int rhalf = tid >> 7;
  const int row0 = blockIdx.x * 32;

  for (int i = tid; i < DIM * DIM; i += 256) sW[i] = W1[i];
  for (int i = tid; i < 32 * DIM; i += 256) {
    int r = i >> 7, c = i & 127;
    sH[r][c] = hbuf[(size_t)(row0 + r) * DIM + c];
  }
  __syncthreads();
  float acc[16];
  float bias = b1[col];
#pragma unroll
  for (int j = 0; j < 16; ++j) acc[j] = bias;
#pragma unroll 4
  for (int k = 0; k < DIM; ++k) {
    float w = sW[k * DIM + col];
#pragma unroll
    for (int j = 0; j < 16; ++j) acc[j] = fmaf(sH[2 * j + rhalf][k], w, acc[j]);
  }
  __syncthreads();
  for (int i = tid; i < DIM * DIM; i += 256) sW[i] = W2[i];
#pragma unroll
  for (int j = 0; j < 16; ++j) sH[2 * j + rhalf][col] = fmaxf(acc[j], 0.f);
  __syncthreads();
  float bias2 = b2[col];
#pragma unroll
  for (int j = 0; j < 16; ++j) acc[j] = bias2;
#pragma unroll 4
  for (int k = 0; k < DIM; ++k) {
    float w = sW[k * DIM + col];
#pragma unroll
    for (int j = 0; j < 16; ++j) acc[j] = fmaf(sH[2 * j + rhalf][k], w, acc[j]);
  }
#pragma unroll
  for (int j = 0; j < 16; ++j)
    hbuf[(size_t)(row0 + 2 * j + rhalf) * DIM + col] = fmaxf(acc[j], 0.f);
}

__global__ __launch_bounds__(256) void bn_stats_kernel(
    const float* __restrict__ h, float* __restrict__ stats) {
  int col = threadIdx.x & 127;
  int rsub = threadIdx.x >> 7;
  int rstep = gridDim.x * 2;
  float s = 0.f, ss = 0.f;
  for (int r = blockIdx.x * 2 + rsub; r < N_NODES; r += rstep) {
    float v = h[(size_t)r * DIM + col];
    s += v;
    ss += v * v;
  }
  __shared__ float ls[256], lss[256];
  ls[threadIdx.x] = s;
  lss[threadIdx.x] = ss;
  __syncthreads();
  if (threadIdx.x < 128) {
    atomicAdd(&stats[col], ls[threadIdx.x] + ls[threadIdx.x + 128]);
    atomicAdd(&stats[DIM + col], lss[threadIdx.x] + lss[threadIdx.x + 128]);
  }
}

__global__ void bn_scale_kernel(const float* __restrict__ stats,
                                const float* __restrict__ gamma,
                                const float* __restrict__ beta,
                                float* __restrict__ sc) {
  int c = threadIdx.x;  // 128
  float mean = stats[c] / (float)N_NODES;
  float var = stats[DIM + c] / (float)N_NODES - mean * mean;
  float scale = gamma[c] * rsqrtf(var + 1e-5f);
  sc[c] = scale;
  sc[DIM + c] = beta[c] - mean * scale;
}

__global__ __launch_bounds__(256) void bn_apply_kernel(
    float* __restrict__ h, const float* __restrict__ sc) {
  size_t total = (size_t)N_NODES * DIM / 4;
  size_t stride = (size_t)gridDim.x * blockDim.x;
  for (size_t i = (size_t)blockIdx.x * blockDim.x + threadIdx.x; i < total;
       i += stride) {
    float4 v = reinterpret_cast<float4*>(h)[i];
    int c = (int)((i * 4) & 127);
    v.x = v.x * sc[c + 0] + sc[DIM + c + 0];
    v.y = v.y * sc[c + 1] + sc[DIM + c + 1];
    v.z = v.z * sc[c + 2] + sc[DIM + c + 2];
    v.w = v.w * sc[c + 3] + sc[DIM + c + 3];
    reinterpret_cast<float4*>(h)[i] = v;
  }
}

extern "C" void kernel_launch(void* const* d_in, const int* in_sizes, int n_in,
                              void* d_out, int out_size, void* d_ws,
                              size_t ws_size, hipStream_t stream) {
  const float* x = (const float*)d_in[0];
  const int* ei = (const int*)d_in[1];
  const float* W1 = (const float*)d_in[3];
  const float* b1 = (const float*)d_in[4];
  const float* W2 = (const float*)d_in[5];
  const float* b2 = (const float*)d_in[6];
  const float* gamma = (const float*)d_in[7];
  const float* beta = (const float*)d_in[8];
  float* out = (float*)d_out;
  int E_ = in_sizes[1] / 2;

  const size_t XB_B = (size_t)N_NODES * DIM * 2;  // 25.6e6
  char* w = (char*)d_ws;

  // ---- Tier1 layout: fixed-stride buckets (no bhist/bscan) ----
  size_t o1 = 0;
  u16* t1_xb = (u16*)(w + o1); o1 += XB_B;
  u16* t1_hb = (u16*)(w + o1); o1 += XB_B;
  u16* t1_Wt1 = (u16*)(w + o1); o1 += 32768;
  u16* t1_Wt2 = (u16*)(w + o1); o1 += 32768;
  u32* t1_packed = (u32*)(w + o1); o1 += (size_t)NB1 * CAP1 * 4;  // 15.2 MB
  float* t1_stats = (float*)(w + o1); o1 += 3072;
  int* t1_gcur = (int*)(w + o1); o1 += 3200;  // NB1 ints, padded
  size_t need1 = o1;

  // ---- Tier2 layout (R12): exact-offset buckets ----
  size_t o2 = 0;
  u16* t2_xb = (u16*)(w + o2); o2 += XB_B;
  u16* t2_hb = (u16*)(w + o2); o2 += XB_B;
  u16* t2_Wt1 = (u16*)(w + o2); o2 += 32768;
  u16* t2_Wt2 = (u16*)(w + o2); o2 += 32768;
  u32* t2_packed = (u32*)(w + o2); o2 += (size_t)E_ * 4;
  int* t2_bcnt = (int*)(w + o2); o2 += 1600;
  float* t2_stats = (float*)(w + o2); o2 += 3072;
  int* t2_boffs = (int*)(w + o2); o2 += 1600;
  int* t2_gcur = (int*)(w + o2); o2 += 1600;
  size_t need2 = o2;

  const int nPartBlocks = (E_ + PT_TILE - 1) / PT_TILE;
  const int nMlpBlocks = (N_NODES + 63) / 64;  // 1563

  if (ws_size >= need1) {
    float* pstats = (float*)t1_xb;  // xb dead after sortgather
    prep1_kernel<<<130, 256, 0, stream>>>(W1, t1_Wt1, W2, t1_Wt2, t1_gcur,
                                          t1_stats);
    part_cvt_kernel<7, NB1><<<nPartBlocks + 1024, PT_THR, 0, stream>>>(
        ei, t1_gcur, t1_packed, E_, x, t1_xb);
    sortgather_kernel<7, 512, CAP1, true><<<NB1, 512, 0, stream>>>(
        t1_packed, nullptr, t1_gcur, (const uint4*)t1_xb, (uint4*)t1_hb);
    mlp_mfma_kernel<<<nMlpBlocks, 256, 0, stream>>>(t1_hb, t1_Wt1, t1_Wt2, b1,
                                                    b2, pstats);
    bn_reduce_kernel<<<32, 256, 0, stream>>>(pstats, t1_stats, nMlpBlocks);
    bn_apply_bf16_kernel<<<2048, 256, 0, stream>>>(
        (const uint4*)t1_hb, t1_stats, gamma, beta, (float4*)out);
  } else if (ws_size >= need2) {
    float* pstats = (float*)t2_xb;
    hipMemsetAsync(t2_bcnt, 0, 1600 + 3072, stream);  // bcnt + stats
    prep2_kernel<<<640, 256, 0, stream>>>(W1, t2_Wt1, W2, t2_Wt2, ei, t2_bcnt,
                                          E_);
    bscan_kernel<<<1, 256, 0, stream>>>(t2_bcnt, t2_boffs, t2_gcur);
    part_cvt_kernel<8, NB2><<<nPartBlocks + 1024, PT_THR, 0, stream>>>(
        ei, t2_gcur, t2_packed, E_, x, t2_xb);
    sortgather_kernel<8, 1024, CAP2, false><<<NB2, 1024, 0, stream>>>(
        t2_packed, t2_boffs, nullptr, (const uint4*)t2_xb, (uint4*)t2_hb);
    mlp_mfma_kernel<<<nMlpBlocks, 256, 0, stream>>>(t2_hb, t2_Wt1, t2_Wt2, b1,
                                                    b2, pstats);
    bn_reduce_kernel<<<32, 256, 0, stream>>>(pstats, t2_stats, nMlpBlocks);
    bn_apply_bf16_kernel<<<2048, 256, 0, stream>>>(
        (const uint4*)t2_hb, t2_stats, gamma, beta, (float4*)out);
  } else {
    // minimal atomic fallback (needs only 768 floats of ws)
    float* s2 = (float*)d_ws;
    hipMemsetAsync(out, 0, (size_t)N_NODES * DIM * sizeof(float), stream);
    hipMemsetAsync(s2, 0, 768 * sizeof(float), stream);
    scatter_kernel<<<4096, 256, 0, stream>>>(x, ei, out, E_);
    add_x_kernel<<<2048, 256, 0, stream>>>(x, out);
    mlp_valu_kernel<<<(N_NODES + 31) / 32, 256, 0, stream>>>(out, W1, b1, W2,
                                                             b2);
    bn_stats_kernel<<<1024, 256, 0, stream>>>(out, s2);
    bn_scale_kernel<<<1, 128, 0, stream>>>(s2, gamma, beta, s2 + 256);
    bn_apply_kernel<<<2048, 256, 0, stream>>>(out, s2 + 256);
  }
}

// Round 14
// 251.199 us; speedup vs baseline: 1.1517x; 1.0318x over previous
//
#include <hip/hip_runtime.h>

#define N_NODES 100000
#define DIM 128
#define PT_TILE 4096  // edges per partition block
#define PT_THR 512
#define NB 391        // ceil(N/256), bucket = dst>>8 (256 nodes per bucket)
#define CAP1 9472     // tier1 fixed per-bucket stride (mean 8184, +14 sigma)
#define CAP2 12288    // tier2 LDS sort capacity (exact offsets)

typedef unsigned int u32;
typedef unsigned short u16;
typedef __attribute__((ext_vector_type(8))) short bf16x8;
typedef __attribute__((ext_vector_type(4))) float f32x4;

__device__ __forceinline__ float bf16_to_f(u16 v) {
  return __uint_as_float(((u32)v) << 16);
}
__device__ __forceinline__ u16 f_to_bf16(float f) {
  u32 b = __float_as_uint(f);
  b += 0x7fff + ((b >> 16) & 1);  // round-to-nearest-even
  return (u16)(b >> 16);
}
__device__ __forceinline__ float blo(u32 q) { return __uint_as_float(q << 16); }
__device__ __forceinline__ float bhi(u32 q) {
  return __uint_as_float(q & 0xffff0000u);
}
__device__ __forceinline__ u32 packbf(float lo, float hi) {
  return ((u32)f_to_bf16(hi) << 16) | (u32)f_to_bf16(lo);
}

// ====== Tier1 prep: cvt_W1 + cvt_W2 + gcur-init + stats-zero ======
__global__ __launch_bounds__(256) void prep1_kernel(
    const float* __restrict__ W1, u16* __restrict__ Wt1,
    const float* __restrict__ W2, u16* __restrict__ Wt2,
    int* __restrict__ gcur, float* __restrict__ stats) {
  int blk = blockIdx.x;
  if (blk < 64) {
    int id = blk * 256 + threadIdx.x;  // id = c*128 + k
    Wt1[id] = f_to_bf16(W1[(id & 127) * DIM + (id >> 7)]);
  } else if (blk < 128) {
    int id = (blk - 64) * 256 + threadIdx.x;
    Wt2[id] = f_to_bf16(W2[(id & 127) * DIM + (id >> 7)]);
  } else if (blk == 128) {
    for (int i = threadIdx.x; i < NB; i += 256) gcur[i] = i * CAP1;
  } else {
    for (int i = threadIdx.x; i < 768; i += 256) stats[i] = 0.f;
  }
}

// ====== Tier2 prep: cvt_W + bhist ======
__global__ __launch_bounds__(256) void prep2_kernel(
    const float* __restrict__ W1, u16* __restrict__ Wt1,
    const float* __restrict__ W2, u16* __restrict__ Wt2,
    const int* __restrict__ ei, int* __restrict__ bcnt, int E_) {
  int blk = blockIdx.x;
  if (blk < 64) {
    int id = blk * 256 + threadIdx.x;
    Wt1[id] = f_to_bf16(W1[(id & 127) * DIM + (id >> 7)]);
  } else if (blk < 128) {
    int id = (blk - 64) * 256 + threadIdx.x;
    Wt2[id] = f_to_bf16(W2[(id & 127) * DIM + (id >> 7)]);
  } else {
    __shared__ int lc[NB];
    for (int i = threadIdx.x; i < NB; i += 256) lc[i] = 0;
    __syncthreads();
    const int* dst = ei + E_;
    int G = 512 * 256;
    int g = (blk - 128) * 256 + threadIdx.x;
    int n4 = E_ >> 2;
    const int4* d4 = (const int4*)dst;
    for (int i = g; i < n4; i += G) {
      int4 v = d4[i];
      atomicAdd(&lc[((u32)v.x) >> 8], 1);
      atomicAdd(&lc[((u32)v.y) >> 8], 1);
      atomicAdd(&lc[((u32)v.z) >> 8], 1);
      atomicAdd(&lc[((u32)v.w) >> 8], 1);
    }
    for (int e = (n4 << 2) + g; e < E_; e += G)
      atomicAdd(&lc[((u32)dst[e]) >> 8], 1);
    __syncthreads();
    for (int i = threadIdx.x; i < NB; i += 256)
      if (lc[i]) atomicAdd(&bcnt[i], lc[i]);
  }
}

__global__ void bscan_kernel(const int* __restrict__ bcnt,
                             int* __restrict__ boffs, int* __restrict__ gcur) {
  __shared__ int s[256];
  int t = threadIdx.x;
  int v0 = (2 * t < NB) ? bcnt[2 * t] : 0;
  int v1 = (2 * t + 1 < NB) ? bcnt[2 * t + 1] : 0;
  int ts = v0 + v1;
  s[t] = ts;
  __syncthreads();
  for (int o = 1; o < 256; o <<= 1) {
    int u = (t >= o) ? s[t - o] : 0;
    __syncthreads();
    s[t] += u;
    __syncthreads();
  }
  int excl = s[t] - ts;
  if (2 * t <= NB) boffs[2 * t] = excl;
  if (2 * t + 1 <= NB) boffs[2 * t + 1] = excl + v0;
  if (2 * t < NB) gcur[2 * t] = excl;
  if (2 * t + 1 < NB) gcur[2 * t + 1] = excl + v0;
}

// ========= partition (+ concurrent cvt_x in disjoint block range) =========
// gcur: tier1 = running cursors pre-set to b*CAP1; tier2 = bscan offsets.
__global__ __launch_bounds__(PT_THR) void part_cvt_kernel(
    const int* __restrict__ ei, int* __restrict__ gcur,
    u32* __restrict__ packed, int E_, const float* __restrict__ x,
    u16* __restrict__ xb) {
  __shared__ u32 keys[PT_TILE];   // 16 KB
  __shared__ u16 bid[PT_TILE];    // 8 KB
  __shared__ int lh[NB];
  __shared__ int lpos[NB];
  __shared__ int gpos[NB];
  __shared__ int ss[PT_THR];
  const int nPart = (E_ + PT_TILE - 1) / PT_TILE;
  const int t = threadIdx.x;

  if (blockIdx.x >= nPart) {
    int cb = blockIdx.x - nPart;  // 0..1023
    int total = N_NODES * DIM / 4;
    int stride = 1024 * PT_THR;
    for (int i = cb * PT_THR + t; i < total; i += stride) {
      float4 v = reinterpret_cast<const float4*>(x)[i];
      ushort4 o;
      o.x = f_to_bf16(v.x);
      o.y = f_to_bf16(v.y);
      o.z = f_to_bf16(v.z);
      o.w = f_to_bf16(v.w);
      reinterpret_cast<ushort4*>(xb)[i] = o;
    }
    return;
  }

  const int base = blockIdx.x * PT_TILE;
  const int cnt = min(PT_TILE, E_ - base);

  for (int i = t; i < NB; i += PT_THR) lh[i] = 0;
  __syncthreads();

  u32 pk[8];
  int bb[8];
#pragma unroll
  for (int k = 0; k < 8; ++k) {
    int e = base + k * PT_THR + t;
    if (k * PT_THR + t < cnt) {
      int src = ei[e];
      u32 dst = (u32)ei[E_ + e];
      bb[k] = (int)(dst >> 8);
      pk[k] = (u32)src | ((dst & 255u) << 17);
      atomicAdd(&lh[bb[k]], 1);
    } else {
      bb[k] = -1;
    }
  }
  __syncthreads();

  int v = (t < NB) ? lh[t] : 0;
  ss[t] = v;
  __syncthreads();
  for (int o = 1; o < PT_THR; o <<= 1) {
    int u = (t >= o) ? ss[t - o] : 0;
    __syncthreads();
    ss[t] += u;
    __syncthreads();
  }
  if (t < NB) {
    lpos[t] = ss[t] - v;
    if (v > 0) gpos[t] = atomicAdd(&gcur[t], v);
  }
  __syncthreads();

#pragma unroll
  for (int k = 0; k < 8; ++k) {
    if (bb[k] >= 0) {
      int p = atomicAdd(&lpos[bb[k]], 1);
      keys[p] = pk[k];
      bid[p] = (u16)bb[k];
    }
  }
  __syncthreads();

  for (int i = t; i < cnt; i += PT_THR) {
    int b = bid[i];
    int startb = lpos[b] - lh[b];
    packed[gpos[b] + (i - startb)] = keys[i];
  }
}

// ===== Fused bucket-sort + gather (256 nodes/bucket, 1024 threads) =====
// FIXED=true: bucket b at packed[b*LCAP], count = gcur[b]-b*LCAP.
// FIXED=false: offsets from boffs.
template <int LCAP, bool FIXED>
__global__ __launch_bounds__(1024) void sortgather_kernel(
    const u32* __restrict__ packed, const int* __restrict__ boffs,
    const int* __restrict__ gcur, const uint4* __restrict__ xb4,
    uint4* __restrict__ hb4) {
  __shared__ u32 sorted_[LCAP];
  __shared__ int hist[256], cur[256], ssc[256];
  __shared__ int nodeoff[257];
  const int b = blockIdx.x;
  const int t = threadIdx.x;
  int base, cnt;
  if (FIXED) {
    base = b * LCAP;
    cnt = gcur[b] - base;
  } else {
    base = boffs[b];
    cnt = boffs[b + 1] - base;
  }
  if (cnt > LCAP) cnt = LCAP;
  if (cnt < 0) cnt = 0;

  if (t < 256) hist[t] = 0;
  __syncthreads();
  for (int i = t; i < cnt; i += 1024)
    atomicAdd(&hist[packed[base + i] >> 17], 1);
  __syncthreads();
  if (t < 256) ssc[t] = hist[t];
  __syncthreads();
  for (int o = 1; o < 256; o <<= 1) {
    int u = 0;
    if (t < 256 && t >= o) u = ssc[t - o];
    __syncthreads();
    if (t < 256) ssc[t] += u;
    __syncthreads();
  }
  if (t < 256) {
    int excl = ssc[t] - hist[t];
    cur[t] = excl;
    nodeoff[t] = excl;
  }
  if (t == 0) nodeoff[256] = cnt;
  __syncthreads();
  for (int i = t; i < cnt; i += 1024) {
    u32 v = packed[base + i];
    int p = atomicAdd(&cur[v >> 17], 1);
    sorted_[p] = v & 0x1FFFFu;
  }
  __syncthreads();

  // ---- gather phase: 16 waves x 16 nodes each ----
  const int wv = t >> 6;
  const int lane = t & 63;
  const int g = lane >> 4;
  const int l = lane & 15;
#pragma unroll 1
  for (int k = 0; k < 16; ++k) {
    int nl = wv + (k << 4);
    int n = b * 256 + nl;
    if (n >= N_NODES) break;
    int beg = nodeoff[nl], end = nodeoff[nl + 1];
    float a0 = 0.f, a1 = 0.f, a2 = 0.f, a3 = 0.f;
    float a4 = 0.f, a5 = 0.f, a6 = 0.f, a7 = 0.f;
    if (g == 0) {  // self row
      uint4 q = xb4[(size_t)n * 16 + l];
      a0 = blo(q.x); a1 = bhi(q.x);
      a2 = blo(q.y); a3 = bhi(q.y);
      a4 = blo(q.z); a5 = bhi(q.z);
      a6 = blo(q.w); a7 = bhi(q.w);
    }
    int j = beg + g;
    for (; j + 12 < end; j += 16) {
      int s0 = sorted_[j], s1 = sorted_[j + 4];
      int s2 = sorted_[j + 8], s3 = sorted_[j + 12];
      uint4 q0 = xb4[(size_t)s0 * 16 + l];
      uint4 q1 = xb4[(size_t)s1 * 16 + l];
      uint4 q2 = xb4[(size_t)s2 * 16 + l];
      uint4 q3 = xb4[(size_t)s3 * 16 + l];
      a0 += blo(q0.x); a1 += bhi(q0.x);
      a2 += blo(q0.y); a3 += bhi(q0.y);
      a4 += blo(q0.z); a5 += bhi(q0.z);
      a6 += blo(q0.w); a7 += bhi(q0.w);
      a0 += blo(q1.x); a1 += bhi(q1.x);
      a2 += blo(q1.y); a3 += bhi(q1.y);
      a4 += blo(q1.z); a5 += bhi(q1.z);
      a6 += blo(q1.w); a7 += bhi(q1.w);
      a0 += blo(q2.x); a1 += bhi(q2.x);
      a2 += blo(q2.y); a3 += bhi(q2.y);
      a4 += blo(q2.z); a5 += bhi(q2.z);
      a6 += blo(q2.w); a7 += bhi(q2.w);
      a0 += blo(q3.x); a1 += bhi(q3.x);
      a2 += blo(q3.y); a3 += bhi(q3.y);
      a4 += blo(q3.z); a5 += bhi(q3.z);
      a6 += blo(q3.w); a7 += bhi(q3.w);
    }
    for (; j < end; j += 4) {
      uint4 q = xb4[(size_t)sorted_[j] * 16 + l];
      a0 += blo(q.x); a1 += bhi(q.x);
      a2 += blo(q.y); a3 += bhi(q.y);
      a4 += blo(q.z); a5 += bhi(q.z);
      a6 += blo(q.w); a7 += bhi(q.w);
    }
    a0 += __shfl_xor(a0, 16); a1 += __shfl_xor(a1, 16);
    a2 += __shfl_xor(a2, 16); a3 += __shfl_xor(a3, 16);
    a4 += __shfl_xor(a4, 16); a5 += __shfl_xor(a5, 16);
    a6 += __shfl_xor(a6, 16); a7 += __shfl_xor(a7, 16);
    a0 += __shfl_xor(a0, 32); a1 += __shfl_xor(a1, 32);
    a2 += __shfl_xor(a2, 32); a3 += __shfl_xor(a3, 32);
    a4 += __shfl_xor(a4, 32); a5 += __shfl_xor(a5, 32);
    a6 += __shfl_xor(a6, 32); a7 += __shfl_xor(a7, 32);
    if (g == 0) {
      uint4 o;
      o.x = packbf(a0, a1);
      o.y = packbf(a2, a3);
      o.z = packbf(a4, a5);
      o.w = packbf(a6, a7);
      hb4[(size_t)n * 16 + l] = o;
    }
  }
}

// ===== MFMA MLP: bf16 h2 in place in hb + streaming per-block partials ====
__global__ __launch_bounds__(256) void mlp_mfma_kernel(
    u16* __restrict__ hb, const u16* __restrict__ Wt1,
    const u16* __restrict__ Wt2, const float* __restrict__ b1,
    const float* __restrict__ b2, float* __restrict__ pstats) {
  __shared__ u16 sH1[4][16 * DIM];  // 16 KB
  __shared__ float sS[4][128], sQ[4][128];  // 4 KB
  const int tid = threadIdx.x;
  const int wv = tid >> 6;
  const int lane = tid & 63;
  const int lr = lane & 15;
  const int lq = lane >> 4;
  const int row0 = blockIdx.x * 64 + wv * 16;

  // ---- layer 1 ----
  bf16x8 a[4];
  {
    int r = row0 + lr;
    if (r > N_NODES - 1) r = N_NODES - 1;
#pragma unroll
    for (int ks = 0; ks < 4; ++ks)
      a[ks] = *reinterpret_cast<const bf16x8*>(hb + (size_t)r * DIM + ks * 32 +
                                               lq * 8);
  }
  f32x4 acc[8];
#pragma unroll
  for (int ct = 0; ct < 8; ++ct) {
    f32x4 c = {0.f, 0.f, 0.f, 0.f};
#pragma unroll
    for (int ks = 0; ks < 4; ++ks) {
      bf16x8 b = *reinterpret_cast<const bf16x8*>(
          Wt1 + (ct * 16 + lr) * DIM + ks * 32 + lq * 8);
      c = __builtin_amdgcn_mfma_f32_16x16x32_bf16(a[ks], b, c, 0, 0, 0);
    }
    acc[ct] = c;
  }
  char* slab = reinterpret_cast<char*>(&sH1[wv][0]);
#pragma unroll
  for (int ct = 0; ct < 8; ++ct) {
    int c = ct * 16 + lr;
    float bias = b1[c];
#pragma unroll
    for (int j = 0; j < 4; ++j) {
      int rl = lq * 4 + j;
      float y = fmaxf(acc[ct][j] + bias, 0.f);
      int byte = rl * 256 + ((c * 2) ^ ((rl & 7) << 4));
      *reinterpret_cast<u16*>(slab + byte) = f_to_bf16(y);
    }
  }
  __syncthreads();

  // ---- layer 2 ----
  bf16x8 a2[4];
#pragma unroll
  for (int ks = 0; ks < 4; ++ks) {
    int byte = lr * 256 + (((ks * 32 + lq * 8) * 2) ^ ((lr & 7) << 4));
    a2[ks] = *reinterpret_cast<const bf16x8*>(slab + byte);
  }
#pragma unroll
  for (int ct = 0; ct < 8; ++ct) {
    f32x4 c = {0.f, 0.f, 0.f, 0.f};
#pragma unroll
    for (int ks = 0; ks < 4; ++ks) {
      bf16x8 b = *reinterpret_cast<const bf16x8*>(
          Wt2 + (ct * 16 + lr) * DIM + ks * 32 + lq * 8);
      c = __builtin_amdgcn_mfma_f32_16x16x32_bf16(a2[ks], b, c, 0, 0, 0);
    }
    acc[ct] = c;
  }
  // ---- epilogue: bf16 h2 back into hb + per-column (s, ss) of quantized ----
  float ls[8], lss[8];
#pragma unroll
  for (int ct = 0; ct < 8; ++ct) {
    int c = ct * 16 + lr;
    float bias = b2[c];
    ls[ct] = 0.f;
    lss[ct] = 0.f;
#pragma unroll
    for (int j = 0; j < 4; ++j) {
      int r = row0 + lq * 4 + j;
      float y = fmaxf(acc[ct][j] + bias, 0.f);
      u16 yq = f_to_bf16(y);
      float yf = bf16_to_f(yq);
      if (r < N_NODES) {
        hb[(size_t)r * DIM + c] = yq;
        ls[ct] += yf;
        lss[ct] += yf * yf;
      }
    }
  }
#pragma unroll
  for (int ct = 0; ct < 8; ++ct) {
    float s = ls[ct], q = lss[ct];
    s += __shfl_xor(s, 16);
    q += __shfl_xor(q, 16);
    s += __shfl_xor(s, 32);
    q += __shfl_xor(q, 32);
    if (lq == 0) {
      sS[wv][ct * 16 + lr] = s;
      sQ[wv][ct * 16 + lr] = q;
    }
  }
  __syncthreads();
  {
    int t = tid;
    float v;
    if (t < 128)
      v = sS[0][t] + sS[1][t] + sS[2][t] + sS[3][t];
    else
      v = sQ[0][t - 128] + sQ[1][t - 128] + sQ[2][t - 128] + sQ[3][t - 128];
    pstats[(size_t)blockIdx.x * 256 + t] = v;  // streaming, no contention
  }
}

// ======================= BatchNorm =======================
__global__ __launch_bounds__(256) void bn_reduce_kernel(
    const float* __restrict__ pstats, float* __restrict__ stats, int nblk) {
  int t = threadIdx.x;
  float v = 0.f;
  for (int i = blockIdx.x; i < nblk; i += gridDim.x)
    v += pstats[(size_t)i * 256 + t];
  atomicAdd(&stats[t], v);
}

__global__ __launch_bounds__(256) void bn_apply_bf16_kernel(
    const uint4* __restrict__ hb4, const float* __restrict__ stats,
    const float* __restrict__ gamma, const float* __restrict__ beta,
    float4* __restrict__ out4) {
  __shared__ float sSc[128], sSh[128];
  int t = threadIdx.x;
  if (t < 128) {
    float mean = stats[t] / (float)N_NODES;
    float var = stats[128 + t] / (float)N_NODES - mean * mean;
    float scale = gamma[t] * rsqrtf(var + 1e-5f);
    sSc[t] = scale;
    sSh[t] = beta[t] - mean * scale;
  }
  __syncthreads();
  int total = N_NODES * 16;  // uint4 per row of 128 bf16
  int stride = gridDim.x * 256;
  for (int i = blockIdx.x * 256 + t; i < total; i += stride) {
    uint4 q = hb4[i];
    int cb = (i & 15) * 8;
    float4 o0, o1;
    o0.x = blo(q.x) * sSc[cb + 0] + sSh[cb + 0];
    o0.y = bhi(q.x) * sSc[cb + 1] + sSh[cb + 1];
    o0.z = blo(q.y) * sSc[cb + 2] + sSh[cb + 2];
    o0.w = bhi(q.y) * sSc[cb + 3] + sSh[cb + 3];
    o1.x = blo(q.z) * sSc[cb + 4] + sSh[cb + 4];
    o1.y = bhi(q.z) * sSc[cb + 5] + sSh[cb + 5];
    o1.z = blo(q.w) * sSc[cb + 6] + sSh[cb + 6];
    o1.w = bhi(q.w) * sSc[cb + 7] + sSh[cb + 7];
    out4[2 * i] = o0;
    out4[2 * i + 1] = o1;
  }
}

// ======================= Minimal atomic fallback =======================
__global__ __launch_bounds__(256) void scatter_kernel(
    const float* __restrict__ x, const int* __restrict__ ei,
    float* __restrict__ h, int E_) {
  long long total = (long long)E_ * 32;
  long long stride = (long long)gridDim.x * blockDim.x;
  for (long long idx = (long long)blockIdx.x * blockDim.x + threadIdx.x;
       idx < total; idx += stride) {
    int e = (int)(idx >> 5);
    int q = (int)(idx & 31);
    float4 v =
        *reinterpret_cast<const float4*>(x + (size_t)ei[e] * DIM + q * 4);
    float* p = h + (size_t)ei[E_ + e] * DIM + q * 4;
    atomicAdd(p + 0, v.x);
    atomicAdd(p + 1, v.y);
    atomicAdd(p + 2, v.z);
    atomicAdd(p + 3, v.w);
  }
}

__global__ __launch_bounds__(256) void add_x_kernel(const float* __restrict__ x,
                                                    float* __restrict__ h) {
  size_t total = (size_t)N_NODES * DIM / 4;
  size_t stride = (size_t)gridDim.x * blockDim.x;
  for (size_t i = (size_t)blockIdx.x * blockDim.x + threadIdx.x; i < total;
       i += stride) {
    float4 v = reinterpret_cast<float4*>(h)[i];
    float4 xv = reinterpret_cast<const float4*>(x)[i];
    v.x += xv.x; v.y += xv.y; v.z += xv.z; v.w += xv.w;
    reinterpret_cast<float4*>(h)[i] = v;
  }
}

__global__ __launch_bounds__(256) void mlp_valu_kernel(
    float* hbuf, const float* __restrict__ W1, const float* __restrict__ b1,
    const float* __restrict__ W2, const float* __restrict__ b2) {
  __shared__ float sW[DIM * DIM];
  __shared__ float sH[32][DIM];
  const int tid = threadIdx.x;
  const int col = tid & 127;
  const int rhalf = tid >> 7;
  const int row0 = blockIdx.x * 32;

  for (int i = tid; i < DIM * DIM; i += 256) sW[i] = W1[i];
  for (int i = tid; i < 32 * DIM; i += 256) {
    int r = i >> 7, c = i & 127;
    sH[r][c] = hbuf[(size_t)(row0 + r) * DIM + c];
  }
  __syncthreads();
  float acc[16];
  float bias = b1[col];
#pragma unroll
  for (int j = 0; j < 16; ++j) acc[j] = bias;
#pragma unroll 4
  for (int k = 0; k < DIM; ++k) {
    float w = sW[k * DIM + col];
#pragma unroll
    for (int j = 0; j < 16; ++j) acc[j] = fmaf(sH[2 * j + rhalf][k], w, acc[j]);
  }
  __syncthreads();
  for (int i = tid; i < DIM * DIM; i += 256) sW[i] = W2[i];
#pragma unroll
  for (int j = 0; j < 16; ++j) sH[2 * j + rhalf][col] = fmaxf(acc[j], 0.f);
  __syncthreads();
  float bias2 = b2[col];
#pragma unroll
  for (int j = 0; j < 16; ++j) acc[j] = bias2;
#pragma unroll 4
  for (int k = 0; k < DIM; ++k) {
    float w = sW[k * DIM + col];
#pragma unroll
    for (int j = 0; j < 16; ++j) acc[j] = fmaf(sH[2 * j + rhalf][k], w, acc[j]);
  }
#pragma unroll
  for (int j = 0; j < 16; ++j)
    hbuf[(size_t)(row0 + 2 * j + rhalf) * DIM + col] = fmaxf(acc[j], 0.f);
}

__global__ __launch_bounds__(256) void bn_stats_kernel(
    const float* __restrict__ h, float* __restrict__ stats) {
  int col = threadIdx.x & 127;
  int rsub = threadIdx.x >> 7;
  int rstep = gridDim.x * 2;
  float s = 0.f, ss = 0.f;
  for (int r = blockIdx.x * 2 + rsub; r < N_NODES; r += rstep) {
    float v = h[(size_t)r * DIM + col];
    s += v;
    ss += v * v;
  }
  __shared__ float ls[256], lss[256];
  ls[threadIdx.x] = s;
  lss[threadIdx.x] = ss;
  __syncthreads();
  if (threadIdx.x < 128) {
    atomicAdd(&stats[col], ls[threadIdx.x] + ls[threadIdx.x + 128]);
    atomicAdd(&stats[DIM + col], lss[threadIdx.x] + lss[threadIdx.x + 128]);
  }
}

__global__ void bn_scale_kernel(const float* __restrict__ stats,
                                const float* __restrict__ gamma,
                                const float* __restrict__ beta,
                                float* __restrict__ sc) {
  int c = threadIdx.x;  // 128
  float mean = stats[c] / (float)N_NODES;
  float var = stats[DIM + c] / (float)N_NODES - mean * mean;
  float scale = gamma[c] * rsqrtf(var + 1e-5f);
  sc[c] = scale;
  sc[DIM + c] = beta[c] - mean * scale;
}

__global__ __launch_bounds__(256) void bn_apply_kernel(
    float* __restrict__ h, const float* __restrict__ sc) {
  size_t total = (size_t)N_NODES * DIM / 4;
  size_t stride = (size_t)gridDim.x * blockDim.x;
  for (size_t i = (size_t)blockIdx.x * blockDim.x + threadIdx.x; i < total;
       i += stride) {
    float4 v = reinterpret_cast<float4*>(h)[i];
    int c = (int)((i * 4) & 127);
    v.x = v.x * sc[c + 0] + sc[DIM + c + 0];
    v.y = v.y * sc[c + 1] + sc[DIM + c + 1];
    v.z = v.z * sc[c + 2] + sc[DIM + c + 2];
    v.w = v.w * sc[c + 3] + sc[DIM + c + 3];
    reinterpret_cast<float4*>(h)[i] = v;
  }
}

extern "C" void kernel_launch(void* const* d_in, const int* in_sizes, int n_in,
                              void* d_out, int out_size, void* d_ws,
                              size_t ws_size, hipStream_t stream) {
  const float* x = (const float*)d_in[0];
  const int* ei = (const int*)d_in[1];
  const float* W1 = (const float*)d_in[3];
  const float* b1 = (const float*)d_in[4];
  const float* W2 = (const float*)d_in[5];
  const float* b2 = (const float*)d_in[6];
  const float* gamma = (const float*)d_in[7];
  const float* beta = (const float*)d_in[8];
  float* out = (float*)d_out;
  int E_ = in_sizes[1] / 2;

  const size_t XB_B = (size_t)N_NODES * DIM * 2;  // 25.6e6
  char* w = (char*)d_ws;

  // ---- Tier1 layout: fixed-stride buckets (no bhist/bscan) ----
  size_t o1 = 0;
  u16* t1_xb = (u16*)(w + o1); o1 += XB_B;
  u16* t1_hb = (u16*)(w + o1); o1 += XB_B;
  u16* t1_Wt1 = (u16*)(w + o1); o1 += 32768;
  u16* t1_Wt2 = (u16*)(w + o1); o1 += 32768;
  u32* t1_packed = (u32*)(w + o1); o1 += (size_t)NB * CAP1 * 4;  // 14.8 MB
  float* t1_stats = (float*)(w + o1); o1 += 3072;
  int* t1_gcur = (int*)(w + o1); o1 += 1600;
  size_t need1 = o1;

  // ---- Tier2 layout: exact-offset buckets ----
  size_t o2 = 0;
  u16* t2_xb = (u16*)(w + o2); o2 += XB_B;
  u16* t2_hb = (u16*)(w + o2); o2 += XB_B;
  u16* t2_Wt1 = (u16*)(w + o2); o2 += 32768;
  u16* t2_Wt2 = (u16*)(w + o2); o2 += 32768;
  u32* t2_packed = (u32*)(w + o2); o2 += (size_t)E_ * 4;
  int* t2_bcnt = (int*)(w + o2); o2 += 1600;
  float* t2_stats = (float*)(w + o2); o2 += 3072;
  int* t2_boffs = (int*)(w + o2); o2 += 1600;
  int* t2_gcur = (int*)(w + o2); o2 += 1600;
  size_t need2 = o2;

  const int nPartBlocks = (E_ + PT_TILE - 1) / PT_TILE;
  const int nMlpBlocks = (N_NODES + 63) / 64;  // 1563

  if (ws_size >= need1) {
    float* pstats = (float*)t1_xb;  // xb dead after sortgather
    prep1_kernel<<<130, 256, 0, stream>>>(W1, t1_Wt1, W2, t1_Wt2, t1_gcur,
                                          t1_stats);
    part_cvt_kernel<<<nPartBlocks + 1024, PT_THR, 0, stream>>>(
        ei, t1_gcur, t1_packed, E_, x, t1_xb);
    sortgather_kernel<CAP1, true><<<NB, 1024, 0, stream>>>(
        t1_packed, nullptr, t1_gcur, (const uint4*)t1_xb, (uint4*)t1_hb);
    mlp_mfma_kernel<<<nMlpBlocks, 256, 0, stream>>>(t1_hb, t1_Wt1, t1_Wt2, b1,
                                                    b2, pstats);
    bn_reduce_kernel<<<32, 256, 0, stream>>>(pstats, t1_stats, nMlpBlocks);
    bn_apply_bf16_kernel<<<2048, 256, 0, stream>>>(
        (const uint4*)t1_hb, t1_stats, gamma, beta, (float4*)out);
  } else if (ws_size >= need2) {
    float* pstats = (float*)t2_xb;
    hipMemsetAsync(t2_bcnt, 0, 1600 + 3072, stream);  // bcnt + stats
    prep2_kernel<<<640, 256, 0, stream>>>(W1, t2_Wt1, W2, t2_Wt2, ei, t2_bcnt,
                                          E_);
    bscan_kernel<<<1, 256, 0, stream>>>(t2_bcnt, t2_boffs, t2_gcur);
    part_cvt_kernel<<<nPartBlocks + 1024, PT_THR, 0, stream>>>(
        ei, t2_gcur, t2_packed, E_, x, t2_xb);
    sortgather_kernel<CAP2, false><<<NB, 1024, 0, stream>>>(
        t2_packed, t2_boffs, nullptr, (const uint4*)t2_xb, (uint4*)t2_hb);
    mlp_mfma_kernel<<<nMlpBlocks, 256, 0, stream>>>(t2_hb, t2_Wt1, t2_Wt2, b1,
                                                    b2, pstats);
    bn_reduce_kernel<<<32, 256, 0, stream>>>(pstats, t2_stats, nMlpBlocks);
    bn_apply_bf16_kernel<<<2048, 256, 0, stream>>>(
        (const uint4*)t2_hb, t2_stats, gamma, beta, (float4*)out);
  } else {
    // minimal atomic fallback (needs only 768 floats of ws)
    float* s2 = (float*)d_ws;
    hipMemsetAsync(out, 0, (size_t)N_NODES * DIM * sizeof(float), stream);
    hipMemsetAsync(s2, 0, 768 * sizeof(float), stream);
    scatter_kernel<<<4096, 256, 0, stream>>>(x, ei, out, E_);
    add_x_kernel<<<2048, 256, 0, stream>>>(x, out);
    mlp_valu_kernel<<<(N_NODES + 31) / 32, 256, 0, stream>>>(out, W1, b1, W2,
                                                             b2);
    bn_stats_kernel<<<1024, 256, 0, stream>>>(out, s2);
    bn_scale_kernel<<<1, 128, 0, stream>>>(s2, gamma, beta, s2 + 256);
    bn_apply_kernel<<<2048, 256, 0, stream>>>(out, s2 + 256);
  }
}

// Round 15
// 246.833 us; speedup vs baseline: 1.1721x; 1.0177x over previous
//
#include <hip/hip_runtime.h>

#define N_NODES 100000
#define DIM 128
#define PT_TILE 4096  // edges per partition block
#define PT_THR 512

// Tier1: 196-node buckets -> 511 blocks (2/CU, balanced), fixed stride
#define NPB1 196
#define NB1 511
#define CAP1 7168  // mean 6272, +11 sigma
// Tier2: 256-node buckets, exact offsets (proven fallback)
#define NPB2 256
#define NB2 391
#define CAP2 12288

typedef unsigned int u32;
typedef unsigned short u16;
typedef __attribute__((ext_vector_type(8))) short bf16x8;
typedef __attribute__((ext_vector_type(4))) float f32x4;

__device__ __forceinline__ float bf16_to_f(u16 v) {
  return __uint_as_float(((u32)v) << 16);
}
__device__ __forceinline__ u16 f_to_bf16(float f) {
  u32 b = __float_as_uint(f);
  b += 0x7fff + ((b >> 16) & 1);  // round-to-nearest-even
  return (u16)(b >> 16);
}
__device__ __forceinline__ float blo(u32 q) { return __uint_as_float(q << 16); }
__device__ __forceinline__ float bhi(u32 q) {
  return __uint_as_float(q & 0xffff0000u);
}
__device__ __forceinline__ u32 packbf(float lo, float hi) {
  return ((u32)f_to_bf16(hi) << 16) | (u32)f_to_bf16(lo);
}

// ====== Tier1 prep: cvt_W1 + cvt_W2 + gcur-init + stats-zero ======
__global__ __launch_bounds__(256) void prep1_kernel(
    const float* __restrict__ W1, u16* __restrict__ Wt1,
    const float* __restrict__ W2, u16* __restrict__ Wt2,
    int* __restrict__ gcur, float* __restrict__ stats) {
  int blk = blockIdx.x;
  if (blk < 64) {
    int id = blk * 256 + threadIdx.x;  // id = c*128 + k
    Wt1[id] = f_to_bf16(W1[(id & 127) * DIM + (id >> 7)]);
  } else if (blk < 128) {
    int id = (blk - 64) * 256 + threadIdx.x;
    Wt2[id] = f_to_bf16(W2[(id & 127) * DIM + (id >> 7)]);
  } else if (blk == 128) {
    for (int i = threadIdx.x; i < NB1; i += 256) gcur[i] = i * CAP1;
  } else {
    for (int i = threadIdx.x; i < 768; i += 256) stats[i] = 0.f;
  }
}

// ====== Tier2 prep: cvt_W + bhist ======
__global__ __launch_bounds__(256) void prep2_kernel(
    const float* __restrict__ W1, u16* __restrict__ Wt1,
    const float* __restrict__ W2, u16* __restrict__ Wt2,
    const int* __restrict__ ei, int* __restrict__ bcnt, int E_) {
  int blk = blockIdx.x;
  if (blk < 64) {
    int id = blk * 256 + threadIdx.x;
    Wt1[id] = f_to_bf16(W1[(id & 127) * DIM + (id >> 7)]);
  } else if (blk < 128) {
    int id = (blk - 64) * 256 + threadIdx.x;
    Wt2[id] = f_to_bf16(W2[(id & 127) * DIM + (id >> 7)]);
  } else {
    __shared__ int lc[NB2];
    for (int i = threadIdx.x; i < NB2; i += 256) lc[i] = 0;
    __syncthreads();
    const int* dst = ei + E_;
    int G = 512 * 256;
    int g = (blk - 128) * 256 + threadIdx.x;
    int n4 = E_ >> 2;
    const int4* d4 = (const int4*)dst;
    for (int i = g; i < n4; i += G) {
      int4 v = d4[i];
      atomicAdd(&lc[((u32)v.x) >> 8], 1);
      atomicAdd(&lc[((u32)v.y) >> 8], 1);
      atomicAdd(&lc[((u32)v.z) >> 8], 1);
      atomicAdd(&lc[((u32)v.w) >> 8], 1);
    }
    for (int e = (n4 << 2) + g; e < E_; e += G)
      atomicAdd(&lc[((u32)dst[e]) >> 8], 1);
    __syncthreads();
    for (int i = threadIdx.x; i < NB2; i += 256)
      if (lc[i]) atomicAdd(&bcnt[i], lc[i]);
  }
}

__global__ void bscan_kernel(const int* __restrict__ bcnt,
                             int* __restrict__ boffs, int* __restrict__ gcur) {
  __shared__ int s[256];
  int t = threadIdx.x;
  int v0 = (2 * t < NB2) ? bcnt[2 * t] : 0;
  int v1 = (2 * t + 1 < NB2) ? bcnt[2 * t + 1] : 0;
  int ts = v0 + v1;
  s[t] = ts;
  __syncthreads();
  for (int o = 1; o < 256; o <<= 1) {
    int u = (t >= o) ? s[t - o] : 0;
    __syncthreads();
    s[t] += u;
    __syncthreads();
  }
  int excl = s[t] - ts;
  if (2 * t <= NB2) boffs[2 * t] = excl;
  if (2 * t + 1 <= NB2) boffs[2 * t + 1] = excl + v0;
  if (2 * t < NB2) gcur[2 * t] = excl;
  if (2 * t + 1 < NB2) gcur[2 * t + 1] = excl + v0;
}

// ========= partition (+ concurrent cvt_x), bucket = dst / NPB =========
template <int NPB, int NBU>
__global__ __launch_bounds__(PT_THR) void part_cvt_kernel(
    const int* __restrict__ ei, int* __restrict__ gcur,
    u32* __restrict__ packed, int E_, const float* __restrict__ x,
    u16* __restrict__ xb) {
  __shared__ u32 keys[PT_TILE];   // 16 KB
  __shared__ u16 bid[PT_TILE];    // 8 KB
  __shared__ int lh[NBU];
  __shared__ int lpos[NBU];
  __shared__ int gpos[NBU];
  __shared__ int ss[PT_THR];
  const int nPart = (E_ + PT_TILE - 1) / PT_TILE;
  const int t = threadIdx.x;

  if (blockIdx.x >= nPart) {
    int cb = blockIdx.x - nPart;  // 0..1023
    int total = N_NODES * DIM / 4;
    int stride = 1024 * PT_THR;
    for (int i = cb * PT_THR + t; i < total; i += stride) {
      float4 v = reinterpret_cast<const float4*>(x)[i];
      ushort4 o;
      o.x = f_to_bf16(v.x);
      o.y = f_to_bf16(v.y);
      o.z = f_to_bf16(v.z);
      o.w = f_to_bf16(v.w);
      reinterpret_cast<ushort4*>(xb)[i] = o;
    }
    return;
  }

  const int base = blockIdx.x * PT_TILE;
  const int cnt = min(PT_TILE, E_ - base);

  for (int i = t; i < NBU; i += PT_THR) lh[i] = 0;
  __syncthreads();

  u32 pk[8];
  int bb[8];
#pragma unroll
  for (int k = 0; k < 8; ++k) {
    int e = base + k * PT_THR + t;
    if (k * PT_THR + t < cnt) {
      int src = ei[e];
      u32 dst = (u32)ei[E_ + e];
      u32 b = dst / NPB;  // constant divisor -> magic mul
      bb[k] = (int)b;
      pk[k] = (u32)src | ((dst - b * NPB) << 17);
      atomicAdd(&lh[bb[k]], 1);
    } else {
      bb[k] = -1;
    }
  }
  __syncthreads();

  int v = (t < NBU) ? lh[t] : 0;
  ss[t] = v;
  __syncthreads();
  for (int o = 1; o < PT_THR; o <<= 1) {
    int u = (t >= o) ? ss[t - o] : 0;
    __syncthreads();
    ss[t] += u;
    __syncthreads();
  }
  if (t < NBU) {
    lpos[t] = ss[t] - v;
    if (v > 0) gpos[t] = atomicAdd(&gcur[t], v);
  }
  __syncthreads();

#pragma unroll
  for (int k = 0; k < 8; ++k) {
    if (bb[k] >= 0) {
      int p = atomicAdd(&lpos[bb[k]], 1);
      keys[p] = pk[k];
      bid[p] = (u16)bb[k];
    }
  }
  __syncthreads();

  for (int i = t; i < cnt; i += PT_THR) {
    int b = bid[i];
    int startb = lpos[b] - lh[b];
    packed[gpos[b] + (i - startb)] = keys[i];
  }
}

// ===== Fused bucket-sort + gather (NPB nodes/bucket, 1024 threads) =====
// FIXED=true: bucket b at packed[b*LCAP], count = gcur[b]-b*LCAP.
// FIXED=false: offsets from boffs.
template <int NPB, int LCAP, bool FIXED>
__global__ __launch_bounds__(1024) void sortgather_kernel(
    const u32* __restrict__ packed, const int* __restrict__ boffs,
    const int* __restrict__ gcur, const uint4* __restrict__ xb4,
    uint4* __restrict__ hb4) {
  __shared__ u32 sorted_[LCAP];
  __shared__ int hist[256], cur[256], ssc[256];
  __shared__ int nodeoff[257];
  const int b = blockIdx.x;
  const int t = threadIdx.x;
  int base, cnt;
  if (FIXED) {
    base = b * LCAP;
    cnt = gcur[b] - base;
  } else {
    base = boffs[b];
    cnt = boffs[b + 1] - base;
  }
  if (cnt > LCAP) cnt = LCAP;
  if (cnt < 0) cnt = 0;

  if (t < 256) hist[t] = 0;
  __syncthreads();
  for (int i = t; i < cnt; i += 1024)
    atomicAdd(&hist[packed[base + i] >> 17], 1);
  __syncthreads();
  if (t < 256) ssc[t] = hist[t];
  __syncthreads();
  for (int o = 1; o < 256; o <<= 1) {
    int u = 0;
    if (t < 256 && t >= o) u = ssc[t - o];
    __syncthreads();
    if (t < 256) ssc[t] += u;
    __syncthreads();
  }
  if (t < 256) {
    int excl = ssc[t] - hist[t];
    cur[t] = excl;
    nodeoff[t] = excl;  // nodeoff[NPB] = cnt lands here when NPB < 256
  }
  if (t == 0) nodeoff[256] = cnt;
  __syncthreads();
  for (int i = t; i < cnt; i += 1024) {
    u32 v = packed[base + i];
    int p = atomicAdd(&cur[v >> 17], 1);
    sorted_[p] = v & 0x1FFFFu;
  }
  __syncthreads();

  // ---- gather phase: 16 waves, NPB nodes round-robin ----
  const int wv = t >> 6;
  const int lane = t & 63;
  const int g = lane >> 4;
  const int l = lane & 15;
  constexpr int K = (NPB + 15) / 16;
#pragma unroll 1
  for (int k = 0; k < K; ++k) {
    int nl = wv + (k << 4);
    if (nl >= NPB) break;
    int n = b * NPB + nl;
    if (n >= N_NODES) break;
    int beg = nodeoff[nl], end = nodeoff[nl + 1];
    float a0 = 0.f, a1 = 0.f, a2 = 0.f, a3 = 0.f;
    float a4 = 0.f, a5 = 0.f, a6 = 0.f, a7 = 0.f;
    if (g == 0) {  // self row
      uint4 q = xb4[(size_t)n * 16 + l];
      a0 = blo(q.x); a1 = bhi(q.x);
      a2 = blo(q.y); a3 = bhi(q.y);
      a4 = blo(q.z); a5 = bhi(q.z);
      a6 = blo(q.w); a7 = bhi(q.w);
    }
    int j = beg + g;
    for (; j + 12 < end; j += 16) {
      int s0 = sorted_[j], s1 = sorted_[j + 4];
      int s2 = sorted_[j + 8], s3 = sorted_[j + 12];
      uint4 q0 = xb4[(size_t)s0 * 16 + l];
      uint4 q1 = xb4[(size_t)s1 * 16 + l];
      uint4 q2 = xb4[(size_t)s2 * 16 + l];
      uint4 q3 = xb4[(size_t)s3 * 16 + l];
      a0 += blo(q0.x); a1 += bhi(q0.x);
      a2 += blo(q0.y); a3 += bhi(q0.y);
      a4 += blo(q0.z); a5 += bhi(q0.z);
      a6 += blo(q0.w); a7 += bhi(q0.w);
      a0 += blo(q1.x); a1 += bhi(q1.x);
      a2 += blo(q1.y); a3 += bhi(q1.y);
      a4 += blo(q1.z); a5 += bhi(q1.z);
      a6 += blo(q1.w); a7 += bhi(q1.w);
      a0 += blo(q2.x); a1 += bhi(q2.x);
      a2 += blo(q2.y); a3 += bhi(q2.y);
      a4 += blo(q2.z); a5 += bhi(q2.z);
      a6 += blo(q2.w); a7 += bhi(q2.w);
      a0 += blo(q3.x); a1 += bhi(q3.x);
      a2 += blo(q3.y); a3 += bhi(q3.y);
      a4 += blo(q3.z); a5 += bhi(q3.z);
      a6 += blo(q3.w); a7 += bhi(q3.w);
    }
    for (; j < end; j += 4) {
      uint4 q = xb4[(size_t)sorted_[j] * 16 + l];
      a0 += blo(q.x); a1 += bhi(q.x);
      a2 += blo(q.y); a3 += bhi(q.y);
      a4 += blo(q.z); a5 += bhi(q.z);
      a6 += blo(q.w); a7 += bhi(q.w);
    }
    a0 += __shfl_xor(a0, 16); a1 += __shfl_xor(a1, 16);
    a2 += __shfl_xor(a2, 16); a3 += __shfl_xor(a3, 16);
    a4 += __shfl_xor(a4, 16); a5 += __shfl_xor(a5, 16);
    a6 += __shfl_xor(a6, 16); a7 += __shfl_xor(a7, 16);
    a0 += __shfl_xor(a0, 32); a1 += __shfl_xor(a1, 32);
    a2 += __shfl_xor(a2, 32); a3 += __shfl_xor(a3, 32);
    a4 += __shfl_xor(a4, 32); a5 += __shfl_xor(a5, 32);
    a6 += __shfl_xor(a6, 32); a7 += __shfl_xor(a7, 32);
    if (g == 0) {
      uint4 o;
      o.x = packbf(a0, a1);
      o.y = packbf(a2, a3);
      o.z = packbf(a4, a5);
      o.w = packbf(a6, a7);
      hb4[(size_t)n * 16 + l] = o;
    }
  }
}

// ===== MFMA MLP: bf16 h2 in place in hb + streaming per-block partials ====
__global__ __launch_bounds__(256) void mlp_mfma_kernel(
    u16* __restrict__ hb, const u16* __restrict__ Wt1,
    const u16* __restrict__ Wt2, const float* __restrict__ b1,
    const float* __restrict__ b2, float* __restrict__ pstats) {
  __shared__ u16 sH1[4][16 * DIM];  // 16 KB
  __shared__ float sS[4][128], sQ[4][128];  // 4 KB
  const int tid = threadIdx.x;
  const int wv = tid >> 6;
  const int lane = tid & 63;
  const int lr = lane & 15;
  const int lq = lane >> 4;
  const int row0 = blockIdx.x * 64 + wv * 16;

  // ---- layer 1 ----
  bf16x8 a[4];
  {
    int r = row0 + lr;
    if (r > N_NODES - 1) r = N_NODES - 1;
#pragma unroll
    for (int ks = 0; ks < 4; ++ks)
      a[ks] = *reinterpret_cast<const bf16x8*>(hb + (size_t)r * DIM + ks * 32 +
                                               lq * 8);
  }
  f32x4 acc[8];
#pragma unroll
  for (int ct = 0; ct < 8; ++ct) {
    f32x4 c = {0.f, 0.f, 0.f, 0.f};
#pragma unroll
    for (int ks = 0; ks < 4; ++ks) {
      bf16x8 b = *reinterpret_cast<const bf16x8*>(
          Wt1 + (ct * 16 + lr) * DIM + ks * 32 + lq * 8);
      c = __builtin_amdgcn_mfma_f32_16x16x32_bf16(a[ks], b, c, 0, 0, 0);
    }
    acc[ct] = c;
  }
  char* slab = reinterpret_cast<char*>(&sH1[wv][0]);
#pragma unroll
  for (int ct = 0; ct < 8; ++ct) {
    int c = ct * 16 + lr;
    float bias = b1[c];
#pragma unroll
    for (int j = 0; j < 4; ++j) {
      int rl = lq * 4 + j;
      float y = fmaxf(acc[ct][j] + bias, 0.f);
      int byte = rl * 256 + ((c * 2) ^ ((rl & 7) << 4));
      *reinterpret_cast<u16*>(slab + byte) = f_to_bf16(y);
    }
  }
  __syncthreads();

  // ---- layer 2 ----
  bf16x8 a2[4];
#pragma unroll
  for (int ks = 0; ks < 4; ++ks) {
    int byte = lr * 256 + (((ks * 32 + lq * 8) * 2) ^ ((lr & 7) << 4));
    a2[ks] = *reinterpret_cast<const bf16x8*>(slab + byte);
  }
#pragma unroll
  for (int ct = 0; ct < 8; ++ct) {
    f32x4 c = {0.f, 0.f, 0.f, 0.f};
#pragma unroll
    for (int ks = 0; ks < 4; ++ks) {
      bf16x8 b = *reinterpret_cast<const bf16x8*>(
          Wt2 + (ct * 16 + lr) * DIM + ks * 32 + lq * 8);
      c = __builtin_amdgcn_mfma_f32_16x16x32_bf16(a2[ks], b, c, 0, 0, 0);
    }
    acc[ct] = c;
  }
  // ---- epilogue: bf16 h2 back into hb + per-column (s, ss) of quantized ----
  float ls[8], lss[8];
#pragma unroll
  for (int ct = 0; ct < 8; ++ct) {
    int c = ct * 16 + lr;
    float bias = b2[c];
    ls[ct] = 0.f;
    lss[ct] = 0.f;
#pragma unroll
    for (int j = 0; j < 4; ++j) {
      int r = row0 + lq * 4 + j;
      float y = fmaxf(acc[ct][j] + bias, 0.f);
      u16 yq = f_to_bf16(y);
      float yf = bf16_to_f(yq);
      if (r < N_NODES) {
        hb[(size_t)r * DIM + c] = yq;
        ls[ct] += yf;
        lss[ct] += yf * yf;
      }
    }
  }
#pragma unroll
  for (int ct = 0; ct < 8; ++ct) {
    float s = ls[ct], q = lss[ct];
    s += __shfl_xor(s, 16);
    q += __shfl_xor(q, 16);
    s += __shfl_xor(s, 32);
    q += __shfl_xor(q, 32);
    if (lq == 0) {
      sS[wv][ct * 16 + lr] = s;
      sQ[wv][ct * 16 + lr] = q;
    }
  }
  __syncthreads();
  {
    int t = tid;
    float v;
    if (t < 128)
      v = sS[0][t] + sS[1][t] + sS[2][t] + sS[3][t];
    else
      v = sQ[0][t - 128] + sQ[1][t - 128] + sQ[2][t - 128] + sQ[3][t - 128];
    pstats[(size_t)blockIdx.x * 256 + t] = v;  // streaming, no contention
  }
}

// ======================= BatchNorm =======================
__global__ __launch_bounds__(256) void bn_reduce_kernel(
    const float* __restrict__ pstats, float* __restrict__ stats, int nblk) {
  int t = threadIdx.x;
  float v = 0.f;
  for (int i = blockIdx.x; i < nblk; i += gridDim.x)
    v += pstats[(size_t)i * 256 + t];
  atomicAdd(&stats[t], v);
}

__global__ __launch_bounds__(256) void bn_apply_bf16_kernel(
    const uint4* __restrict__ hb4, const float* __restrict__ stats,
    const float* __restrict__ gamma, const float* __restrict__ beta,
    float4* __restrict__ out4) {
  __shared__ float sSc[128], sSh[128];
  int t = threadIdx.x;
  if (t < 128) {
    float mean = stats[t] / (float)N_NODES;
    float var = stats[128 + t] / (float)N_NODES - mean * mean;
    float scale = gamma[t] * rsqrtf(var + 1e-5f);
    sSc[t] = scale;
    sSh[t] = beta[t] - mean * scale;
  }
  __syncthreads();
  int total = N_NODES * 16;  // uint4 per row of 128 bf16
  int stride = gridDim.x * 256;
  for (int i = blockIdx.x * 256 + t; i < total; i += stride) {
    uint4 q = hb4[i];
    int cb = (i & 15) * 8;
    float4 o0, o1;
    o0.x = blo(q.x) * sSc[cb + 0] + sSh[cb + 0];
    o0.y = bhi(q.x) * sSc[cb + 1] + sSh[cb + 1];
    o0.z = blo(q.y) * sSc[cb + 2] + sSh[cb + 2];
    o0.w = bhi(q.y) * sSc[cb + 3] + sSh[cb + 3];
    o1.x = blo(q.z) * sSc[cb + 4] + sSh[cb + 4];
    o1.y = bhi(q.z) * sSc[cb + 5] + sSh[cb + 5];
    o1.z = blo(q.w) * sSc[cb + 6] + sSh[cb + 6];
    o1.w = bhi(q.w) * sSc[cb + 7] + sSh[cb + 7];
    out4[2 * i] = o0;
    out4[2 * i + 1] = o1;
  }
}

// ======================= Minimal atomic fallback =======================
__global__ __launch_bounds__(256) void scatter_kernel(
    const float* __restrict__ x, const int* __restrict__ ei,
    float* __restrict__ h, int E_) {
  long long total = (long long)E_ * 32;
  long long stride = (long long)gridDim.x * blockDim.x;
  for (long long idx = (long long)blockIdx.x * blockDim.x + threadIdx.x;
       idx < total; idx += stride) {
    int e = (int)(idx >> 5);
    int q = (int)(idx & 31);
    float4 v =
        *reinterpret_cast<const float4*>(x + (size_t)ei[e] * DIM + q * 4);
    float* p = h + (size_t)ei[E_ + e] * DIM + q * 4;
    atomicAdd(p + 0, v.x);
    atomicAdd(p + 1, v.y);
    atomicAdd(p + 2, v.z);
    atomicAdd(p + 3, v.w);
  }
}

__global__ __launch_bounds__(256) void add_x_kernel(const float* __restrict__ x,
                                                    float* __restrict__ h) {
  size_t total = (size_t)N_NODES * DIM / 4;
  size_t stride = (size_t)gridDim.x * blockDim.x;
  for (size_t i = (size_t)blockIdx.x * blockDim.x + threadIdx.x; i < total;
       i += stride) {
    float4 v = reinterpret_cast<float4*>(h)[i];
    float4 xv = reinterpret_cast<const float4*>(x)[i];
    v.x += xv.x; v.y += xv.y; v.z += xv.z; v.w += xv.w;
    reinterpret_cast<float4*>(h)[i] = v;
  }
}

__global__ __launch_bounds__(256) void mlp_valu_kernel(
    float* hbuf, const float* __restrict__ W1, const float* __restrict__ b1,
    const float* __restrict__ W2, const float* __restrict__ b2) {
  __shared__ float sW[DIM * DIM];
  __shared__ float sH[32][DIM];
  const int tid = threadIdx.x;
  const int col = tid & 127;
  const int rhalf = tid >> 7;
  const int row0 = blockIdx.x * 32;

  for (int i = tid; i < DIM * DIM; i += 256) sW[i] = W1[i];
  for (int i = tid; i < 32 * DIM; i += 256) {
    int r = i >> 7, c = i & 127;
    sH[r][c] = hbuf[(size_t)(row0 + r) * DIM + c];
  }
  __syncthreads();
  float acc[16];
  float bias = b1[col];
#pragma unroll
  for (int j = 0; j < 16; ++j) acc[j] = bias;
#pragma unroll 4
  for (int k = 0; k < DIM; ++k) {
    float w = sW[k * DIM + col];
#pragma unroll
    for (int j = 0; j < 16; ++j) acc[j] = fmaf(sH[2 * j + rhalf][k], w, acc[j]);
  }
  __syncthreads();
  for (int i = tid; i < DIM * DIM; i += 256) sW[i] = W2[i];
#pragma unroll
  for (int j = 0; j < 16; ++j) sH[2 * j + rhalf][col] = fmaxf(acc[j], 0.f);
  __syncthreads();
  float bias2 = b2[col];
#pragma unroll
  for (int j = 0; j < 16; ++j) acc[j] = bias2;
#pragma unroll 4
  for (int k = 0; k < DIM; ++k) {
    float w = sW[k * DIM + col];
#pragma unroll
    for (int j = 0; j < 16; ++j) acc[j] = fmaf(sH[2 * j + rhalf][k], w, acc[j]);
  }
#pragma unroll
  for (int j = 0; j < 16; ++j)
    hbuf[(size_t)(row0 + 2 * j + rhalf) * DIM + col] = fmaxf(acc[j], 0.f);
}

__global__ __launch_bounds__(256) void bn_stats_kernel(
    const float* __restrict__ h, float* __restrict__ stats) {
  int col = threadIdx.x & 127;
  int rsub = threadIdx.x >> 7;
  int rstep = gridDim.x * 2;
  float s = 0.f, ss = 0.f;
  for (int r = blockIdx.x * 2 + rsub; r < N_NODES; r += rstep) {
    float v = h[(size_t)r * DIM + col];
    s += v;
    ss += v * v;
  }
  __shared__ float ls[256], lss[256];
  ls[threadIdx.x] = s;
  lss[threadIdx.x] = ss;
  __syncthreads();
  if (threadIdx.x < 128) {
    atomicAdd(&stats[col], ls[threadIdx.x] + ls[threadIdx.x + 128]);
    atomicAdd(&stats[DIM + col], lss[threadIdx.x] + lss[threadIdx.x + 128]);
  }
}

__global__ void bn_scale_kernel(const float* __restrict__ stats,
                                const float* __restrict__ gamma,
                                const float* __restrict__ beta,
                                float* __restrict__ sc) {
  int c = threadIdx.x;  // 128
  float mean = stats[c] / (float)N_NODES;
  float var = stats[DIM + c] / (float)N_NODES - mean * mean;
  float scale = gamma[c] * rsqrtf(var + 1e-5f);
  sc[c] = scale;
  sc[DIM + c] = beta[c] - mean * scale;
}

__global__ __launch_bounds__(256) void bn_apply_kernel(
    float* __restrict__ h, const float* __restrict__ sc) {
  size_t total = (size_t)N_NODES * DIM / 4;
  size_t stride = (size_t)gridDim.x * blockDim.x;
  for (size_t i = (size_t)blockIdx.x * blockDim.x + threadIdx.x; i < total;
       i += stride) {
    float4 v = reinterpret_cast<float4*>(h)[i];
    int c = (int)((i * 4) & 127);
    v.x = v.x * sc[c + 0] + sc[DIM + c + 0];
    v.y = v.y * sc[c + 1] + sc[DIM + c + 1];
    v.z = v.z * sc[c + 2] + sc[DIM + c + 2];
    v.w = v.w * sc[c + 3] + sc[DIM + c + 3];
    reinterpret_cast<float4*>(h)[i] = v;
  }
}

extern "C" void kernel_launch(void* const* d_in, const int* in_sizes, int n_in,
                              void* d_out, int out_size, void* d_ws,
                              size_t ws_size, hipStream_t stream) {
  const float* x = (const float*)d_in[0];
  const int* ei = (const int*)d_in[1];
  const float* W1 = (const float*)d_in[3];
  const float* b1 = (const float*)d_in[4];
  const float* W2 = (const float*)d_in[5];
  const float* b2 = (const float*)d_in[6];
  const float* gamma = (const float*)d_in[7];
  const float* beta = (const float*)d_in[8];
  float* out = (float*)d_out;
  int E_ = in_sizes[1] / 2;

  const size_t XB_B = (size_t)N_NODES * DIM * 2;  // 25.6e6
  char* w = (char*)d_ws;

  // ---- Tier1 layout: 511 fixed-stride buckets ----
  size_t o1 = 0;
  u16* t1_xb = (u16*)(w + o1); o1 += XB_B;
  u16* t1_hb = (u16*)(w + o1); o1 += XB_B;
  u16* t1_Wt1 = (u16*)(w + o1); o1 += 32768;
  u16* t1_Wt2 = (u16*)(w + o1); o1 += 32768;
  u32* t1_packed = (u32*)(w + o1);
  o1 += ((size_t)NB1 * CAP1 + 8192) * 4;  // 14.7 MB + overflow pad
  float* t1_stats = (float*)(w + o1); o1 += 3072;
  int* t1_gcur = (int*)(w + o1); o1 += 2560;
  size_t need1 = o1;

  // ---- Tier2 layout: exact-offset 391 buckets ----
  size_t o2 = 0;
  u16* t2_xb = (u16*)(w + o2); o2 += XB_B;
  u16* t2_hb = (u16*)(w + o2); o2 += XB_B;
  u16* t2_Wt1 = (u16*)(w + o2); o2 += 32768;
  u16* t2_Wt2 = (u16*)(w + o2); o2 += 32768;
  u32* t2_packed = (u32*)(w + o2); o2 += (size_t)E_ * 4;
  int* t2_bcnt = (int*)(w + o2); o2 += 1600;
  float* t2_stats = (float*)(w + o2); o2 += 3072;
  int* t2_boffs = (int*)(w + o2); o2 += 1600;
  int* t2_gcur = (int*)(w + o2); o2 += 1600;
  size_t need2 = o2;

  const int nPartBlocks = (E_ + PT_TILE - 1) / PT_TILE;
  const int nMlpBlocks = (N_NODES + 63) / 64;  // 1563

  if (ws_size >= need1) {
    float* pstats = (float*)t1_xb;  // xb dead after sortgather
    prep1_kernel<<<130, 256, 0, stream>>>(W1, t1_Wt1, W2, t1_Wt2, t1_gcur,
                                          t1_stats);
    part_cvt_kernel<NPB1, NB1><<<nPartBlocks + 1024, PT_THR, 0, stream>>>(
        ei, t1_gcur, t1_packed, E_, x, t1_xb);
    sortgather_kernel<NPB1, CAP1, true><<<NB1, 1024, 0, stream>>>(
        t1_packed, nullptr, t1_gcur, (const uint4*)t1_xb, (uint4*)t1_hb);
    mlp_mfma_kernel<<<nMlpBlocks, 256, 0, stream>>>(t1_hb, t1_Wt1, t1_Wt2, b1,
                                                    b2, pstats);
    bn_reduce_kernel<<<32, 256, 0, stream>>>(pstats, t1_stats, nMlpBlocks);
    bn_apply_bf16_kernel<<<2048, 256, 0, stream>>>(
        (const uint4*)t1_hb, t1_stats, gamma, beta, (float4*)out);
  } else if (ws_size >= need2) {
    float* pstats = (float*)t2_xb;
    hipMemsetAsync(t2_bcnt, 0, 1600 + 3072, stream);  // bcnt + stats
    prep2_kernel<<<640, 256, 0, stream>>>(W1, t2_Wt1, W2, t2_Wt2, ei, t2_bcnt,
                                          E_);
    bscan_kernel<<<1, 256, 0, stream>>>(t2_bcnt, t2_boffs, t2_gcur);
    part_cvt_kernel<NPB2, NB2><<<nPartBlocks + 1024, PT_THR, 0, stream>>>(
        ei, t2_gcur, t2_packed, E_, x, t2_xb);
    sortgather_kernel<NPB2, CAP2, false><<<NB2, 1024, 0, stream>>>(
        t2_packed, t2_boffs, nullptr, (const uint4*)t2_xb, (uint4*)t2_hb);
    mlp_mfma_kernel<<<nMlpBlocks, 256, 0, stream>>>(t2_hb, t2_Wt1, t2_Wt2, b1,
                                                    b2, pstats);
    bn_reduce_kernel<<<32, 256, 0, stream>>>(pstats, t2_stats, nMlpBlocks);
    bn_apply_bf16_kernel<<<2048, 256, 0, stream>>>(
        (const uint4*)t2_hb, t2_stats, gamma, beta, (float4*)out);
  } else {
    // minimal atomic fallback (needs only 768 floats of ws)
    float* s2 = (float*)d_ws;
    hipMemsetAsync(out, 0, (size_t)N_NODES * DIM * sizeof(float), stream);
    hipMemsetAsync(s2, 0, 768 * sizeof(float), stream);
    scatter_kernel<<<4096, 256, 0, stream>>>(x, ei, out, E_);
    add_x_kernel<<<2048, 256, 0, stream>>>(x, out);
    mlp_valu_kernel<<<(N_NODES + 31) / 32, 256, 0, stream>>>(out, W1, b1, W2,
                                                             b2);
    bn_stats_kernel<<<1024, 256, 0, stream>>>(out, s2);
    bn_scale_kernel<<<1, 128, 0, stream>>>(s2, gamma, beta, s2 + 256);
    bn_apply_kernel<<<2048, 256, 0, stream>>>(out, s2 + 256);
  }
}